// Round 1
// baseline (474.423 us; speedup 1.0000x reference)
//
#include <hip/hip_runtime.h>
#include <math.h>

#define IMG 224
#define NPIX 50176
#define BATCH 64
#define NBANDS 8
#define EDIM 256

// ---------------------------------------------------------------- gray ----
__global__ __launch_bounds__(256) void gray_kernel(const float* __restrict__ x,
                                                   float* __restrict__ gray) {
  int p = blockIdx.x * 256 + threadIdx.x;   // 0..50175 (196 blocks * 256)
  int b = blockIdx.y;
  const float* xb = x + (size_t)b * 3 * NPIX;
  gray[(size_t)b * NPIX + p] = (xb[p] + xb[NPIX + p] + xb[2 * NPIX + p]) * (1.0f / 3.0f);
}

// ------------------------------------------------- twiddle + band table ---
__global__ __launch_bounds__(256) void table_kernel(float* __restrict__ Wc,
                                                    float* __restrict__ Wsn,
                                                    unsigned char* __restrict__ band) {
  int p = blockIdx.x * 256 + threadIdx.x;   // 0..50175
  int u = p / IMG, v = p % IMG;
  int m = (u * v) % IMG;
  double ang = -2.0 * 3.14159265358979323846 * (double)m / (double)IMG;
  Wc[p]  = (float)cos(ang);
  Wsn[p] = (float)sin(ang);
  // radial band index, replicating reference fp32 arithmetic exactly
  int dx = v - 112, dy = u - 112;
  float r = sqrtf((float)(dx * dx + dy * dy));
  float step = (float)(158.39191898578665 / 8.0);  // float32(224/sqrt(2)/8)
  unsigned char bd = 255;
#pragma unroll
  for (int k = 0; k < 8; k++) {
    float lo = step * (float)k;
    float hi = step * (float)(k + 1);
    if (r >= lo && r < hi) bd = (unsigned char)k;
  }
  band[p] = bd;
}

// ------------------------------------------------------- stage A: X * W ---
// Y[b,h,v] = sum_w gray[b,h,w] * (cos - i sin)(2*pi*w*v/224)
__global__ __launch_bounds__(256) void dftA_kernel(const float* __restrict__ gray,
                                                   const float* __restrict__ Wc,
                                                   const float* __restrict__ Wsn,
                                                   float* __restrict__ Yre,
                                                   float* __restrict__ Yim) {
  int b = blockIdx.z;
  int m0 = blockIdx.y * 64, n0 = blockIdx.x * 64;
  __shared__ float As[32][68];   // transposed A tile: As[kk][r], ld=68 (bank-friendly, 16B aligned)
  __shared__ float Bc[32][64];
  __shared__ float Bs[32][64];
  int tid = threadIdx.x;
  int tr = tid >> 4, tc = tid & 15;
  float ar[4][4] = {{0}}, ai[4][4] = {{0}};
  const float* gb = gray + (size_t)b * NPIX;

  for (int k0 = 0; k0 < IMG; k0 += 32) {
#pragma unroll
    for (int i = 0; i < 8; i++) {
      int lin = tid + i * 256;
      int r = lin >> 5, kk = lin & 31;
      int row = m0 + r;
      As[kk][r] = (row < IMG) ? gb[row * IMG + k0 + kk] : 0.0f;
    }
#pragma unroll
    for (int i = 0; i < 8; i++) {
      int lin = tid + i * 256;
      int c = lin & 63, kk = lin >> 6;
      int col = n0 + c;
      float vc = 0.0f, vs = 0.0f;
      if (col < IMG) { int gi = (k0 + kk) * IMG + col; vc = Wc[gi]; vs = Wsn[gi]; }
      Bc[kk][c] = vc;
      Bs[kk][c] = vs;
    }
    __syncthreads();
#pragma unroll
    for (int kk = 0; kk < 32; kk++) {
      float4 a4 = *(const float4*)&As[kk][tr << 2];
      float4 c4 = *(const float4*)&Bc[kk][tc << 2];
      float4 s4 = *(const float4*)&Bs[kk][tc << 2];
      float av[4] = {a4.x, a4.y, a4.z, a4.w};
      float cv[4] = {c4.x, c4.y, c4.z, c4.w};
      float sv[4] = {s4.x, s4.y, s4.z, s4.w};
#pragma unroll
      for (int i = 0; i < 4; i++)
#pragma unroll
        for (int j = 0; j < 4; j++) {
          ar[i][j] += av[i] * cv[j];
          ai[i][j] += av[i] * sv[j];
        }
    }
    __syncthreads();
  }

  int col0 = n0 + (tc << 2);
  if (col0 < IMG) {
#pragma unroll
    for (int i = 0; i < 4; i++) {
      int row = m0 + (tr << 2) + i;
      if (row < IMG) {
        size_t o = (size_t)b * NPIX + row * IMG + col0;
        *(float4*)&Yre[o] = make_float4(ar[i][0], ar[i][1], ar[i][2], ar[i][3]);
        *(float4*)&Yim[o] = make_float4(ai[i][0], ai[i][1], ai[i][2], ai[i][3]);
      }
    }
  }
}

// ------------------------------------------------------- stage B: W * Y ---
// F[b,u,v] = sum_h (c+i*s)[u,h] * Y[b,h,v]; epilogue: log1p(|F|), fftshift
__global__ __launch_bounds__(256) void dftB_kernel(const float* __restrict__ Wc,
                                                   const float* __restrict__ Wsn,
                                                   const float* __restrict__ Yre,
                                                   const float* __restrict__ Yim,
                                                   float* __restrict__ mag) {
  int b = blockIdx.z;
  int m0 = blockIdx.y * 64, n0 = blockIdx.x * 64;
  __shared__ float Ac[32][68];
  __shared__ float An[32][68];
  __shared__ float Br[32][64];
  __shared__ float Bi[32][64];
  int tid = threadIdx.x;
  int tr = tid >> 4, tc = tid & 15;
  float fr[4][4] = {{0}}, fi[4][4] = {{0}};
  const float* yre = Yre + (size_t)b * NPIX;
  const float* yim = Yim + (size_t)b * NPIX;

  for (int k0 = 0; k0 < IMG; k0 += 32) {
#pragma unroll
    for (int i = 0; i < 8; i++) {
      int lin = tid + i * 256;
      int r = lin >> 5, kk = lin & 31;
      int row = m0 + r;
      float vc = 0.0f, vn = 0.0f;
      if (row < IMG) { int gi = row * IMG + k0 + kk; vc = Wc[gi]; vn = Wsn[gi]; }
      Ac[kk][r] = vc;
      An[kk][r] = vn;
    }
#pragma unroll
    for (int i = 0; i < 8; i++) {
      int lin = tid + i * 256;
      int c = lin & 63, kk = lin >> 6;
      int col = n0 + c;
      float vr = 0.0f, vi = 0.0f;
      if (col < IMG) { int gi = (k0 + kk) * IMG + col; vr = yre[gi]; vi = yim[gi]; }
      Br[kk][c] = vr;
      Bi[kk][c] = vi;
    }
    __syncthreads();
#pragma unroll
    for (int kk = 0; kk < 32; kk++) {
      float4 a4 = *(const float4*)&Ac[kk][tr << 2];
      float4 n4 = *(const float4*)&An[kk][tr << 2];
      float4 r4 = *(const float4*)&Br[kk][tc << 2];
      float4 i4 = *(const float4*)&Bi[kk][tc << 2];
      float ac[4] = {a4.x, a4.y, a4.z, a4.w};
      float an[4] = {n4.x, n4.y, n4.z, n4.w};
      float br[4] = {r4.x, r4.y, r4.z, r4.w};
      float bi[4] = {i4.x, i4.y, i4.z, i4.w};
#pragma unroll
      for (int i = 0; i < 4; i++)
#pragma unroll
        for (int j = 0; j < 4; j++) {
          fr[i][j] += ac[i] * br[j] - an[i] * bi[j];
          fi[i][j] += ac[i] * bi[j] + an[i] * br[j];
        }
    }
    __syncthreads();
  }

  int col0 = n0 + (tc << 2);
  if (col0 < IMG) {
    int vs0 = col0 + 112; if (vs0 >= IMG) vs0 -= IMG;   // fftshift cols (groups of 4 never straddle)
#pragma unroll
    for (int i = 0; i < 4; i++) {
      int row = m0 + (tr << 2) + i;
      if (row < IMG) {
        int us = row + 112; if (us >= IMG) us -= IMG;   // fftshift rows
        float4 mv;
        mv.x = log1pf(sqrtf(fr[i][0] * fr[i][0] + fi[i][0] * fi[i][0]));
        mv.y = log1pf(sqrtf(fr[i][1] * fr[i][1] + fi[i][1] * fi[i][1]));
        mv.z = log1pf(sqrtf(fr[i][2] * fr[i][2] + fi[i][2] * fi[i][2]));
        mv.w = log1pf(sqrtf(fr[i][3] * fr[i][3] + fi[i][3] * fi[i][3]));
        *(float4*)&mag[(size_t)b * NPIX + us * IMG + vs0] = mv;
      }
    }
  }
}

// ----------------------------------------------------- per-image stats ----
// stats[b][0]=gsum [1]=gsumsq [2+k]=s1 [10+k]=s2 [18+k]=max [26+k]=count
__global__ __launch_bounds__(256) void stats_kernel(const float* __restrict__ mag,
                                                    const unsigned char* __restrict__ band,
                                                    float* __restrict__ stats) {
  int b = blockIdx.x;
  int tid = threadIdx.x;
  const float* mb = mag + (size_t)b * NPIX;
  float gsum = 0.0f, gsq = 0.0f;
  float s1[8] = {0}, s2[8] = {0}, cnt[8] = {0}, mx[8];
#pragma unroll
  for (int k = 0; k < 8; k++) mx[k] = -1e30f;

  for (int p = tid; p < NPIX; p += 256) {   // 196 exact iterations
    float v = mb[p];
    int bt = band[p];
    gsum += v;
    gsq += v * v;
#pragma unroll
    for (int k = 0; k < 8; k++) {
      bool m = (bt == k);
      s1[k]  += m ? v : 0.0f;
      s2[k]  += m ? v * v : 0.0f;
      cnt[k] += m ? 1.0f : 0.0f;
      mx[k]   = m ? fmaxf(mx[k], v) : mx[k];
    }
  }

  float vals[34];
  vals[0] = gsum; vals[1] = gsq;
#pragma unroll
  for (int k = 0; k < 8; k++) {
    vals[2 + k] = s1[k]; vals[10 + k] = s2[k]; vals[18 + k] = mx[k]; vals[26 + k] = cnt[k];
  }
#pragma unroll
  for (int i = 0; i < 34; i++) {
    float v = vals[i];
    const bool isMax = (i >= 18 && i < 26);
#pragma unroll
    for (int off = 32; off > 0; off >>= 1) {
      float o = __shfl_down(v, off);
      v = isMax ? fmaxf(v, o) : (v + o);
    }
    vals[i] = v;
  }
  __shared__ float red[4][34];
  int lane = tid & 63, w = tid >> 6;
  if (lane == 0) {
#pragma unroll
    for (int i = 0; i < 34; i++) red[w][i] = vals[i];
  }
  __syncthreads();
  if (tid < 34) {
    bool isMax = (tid >= 18 && tid < 26);
    float v = red[0][tid];
    for (int ww = 1; ww < 4; ww++) v = isMax ? fmaxf(v, red[ww][tid]) : (v + red[ww][tid]);
    stats[b * 34 + tid] = v;
  }
}

// --------------------------------------------------------------- MLP ------
__global__ __launch_bounds__(256) void mlp_kernel(const float* __restrict__ stats,
                                                  const float* __restrict__ W1,
                                                  const float* __restrict__ b1,
                                                  const float* __restrict__ gamma,
                                                  const float* __restrict__ beta,
                                                  const float* __restrict__ W2,
                                                  const float* __restrict__ b2,
                                                  float* __restrict__ out) {
  int bk = blockIdx.x;         // b*8 + band
  int b = bk >> 3, k = bk & 7;
  int e = threadIdx.x;
  const float* st = stats + b * 34;
  const float N = (float)NPIX;

  float mu = st[0] / N;
  float varg = fmaxf(st[1] - N * mu * mu, 0.0f) / (N - 1.0f);
  float sd = sqrtf(varg) + 1e-6f;

  float s1r = st[2 + k], s2r = st[10 + k], mxr = st[18 + k], cntk = st[26 + k];
  float ms = cntk + 1e-6f;
  float s1n = (s1r - mu * cntk) / sd;
  float s2n = (s2r - 2.0f * mu * s1r + mu * mu * cntk) / (sd * sd);
  float mean_k = s1n / ms;
  float var_num = s2n - 2.0f * mean_k * s1n + mean_k * mean_k * cntk;
  float std_k = sqrtf(var_num / ms + 1e-6f);
  float max_k = (mxr - mu) / sd;

  float h = mean_k * W1[e] + std_k * W1[EDIM + e] + max_k * W1[2 * EDIM + e] + b1[e];

  // LayerNorm over the 256 lanes (1 elem/thread)
  float s = h, q = h * h;
#pragma unroll
  for (int off = 32; off > 0; off >>= 1) {
    s += __shfl_down(s, off);
    q += __shfl_down(q, off);
  }
  __shared__ float rs[4], rq[4];
  __shared__ float hmS, hvS;
  if ((e & 63) == 0) { rs[e >> 6] = s; rq[e >> 6] = q; }
  __syncthreads();
  if (e == 0) {
    float ts = rs[0] + rs[1] + rs[2] + rs[3];
    float tq = rq[0] + rq[1] + rq[2] + rq[3];
    float hm = ts / 256.0f;
    hmS = hm;
    hvS = fmaxf(tq / 256.0f - hm * hm, 0.0f);
  }
  __syncthreads();
  float hn = (h - hmS) / sqrtf(hvS + 1e-5f) * gamma[e] + beta[e];
  float hr = fmaxf(hn, 0.0f);

  __shared__ float hs[EDIM];
  hs[e] = hr;
  __syncthreads();

  float acc = b2[e];
#pragma unroll 8
  for (int j = 0; j < EDIM; j++) acc += hs[j] * W2[j * EDIM + e];
  out[(size_t)bk * EDIM + e] = acc;
}

// ------------------------------------------------------------- launch -----
extern "C" void kernel_launch(void* const* d_in, const int* in_sizes, int n_in,
                              void* d_out, int out_size, void* d_ws, size_t ws_size,
                              hipStream_t stream) {
  const float* x     = (const float*)d_in[0];
  const float* W1    = (const float*)d_in[1];
  const float* b1    = (const float*)d_in[2];
  const float* gamma = (const float*)d_in[3];
  const float* beta  = (const float*)d_in[4];
  const float* W2    = (const float*)d_in[5];
  const float* b2    = (const float*)d_in[6];
  float* out = (float*)d_out;

  float* ws = (float*)d_ws;
  float* gray = ws;                                  // B*NPIX floats (later reused as mag)
  float* Yre  = gray + (size_t)BATCH * NPIX;
  float* Yim  = Yre + (size_t)BATCH * NPIX;
  float* Wc   = Yim + (size_t)BATCH * NPIX;
  float* Wsn  = Wc + NPIX;
  float* stats = Wsn + NPIX;
  unsigned char* band = (unsigned char*)(stats + BATCH * 34);

  gray_kernel<<<dim3(NPIX / 256, BATCH), dim3(256), 0, stream>>>(x, gray);
  table_kernel<<<dim3(NPIX / 256), dim3(256), 0, stream>>>(Wc, Wsn, band);
  dftA_kernel<<<dim3(4, 4, BATCH), dim3(256), 0, stream>>>(gray, Wc, Wsn, Yre, Yim);
  dftB_kernel<<<dim3(4, 4, BATCH), dim3(256), 0, stream>>>(Wc, Wsn, Yre, Yim, gray);
  stats_kernel<<<dim3(BATCH), dim3(256), 0, stream>>>(gray, band, stats);
  mlp_kernel<<<dim3(BATCH * NBANDS), dim3(256), 0, stream>>>(stats, W1, b1, gamma, beta, W2, b2, out);
}

// Round 2
// 172.851 us; speedup vs baseline: 2.7447x; 2.7447x over previous
//
#include <hip/hip_runtime.h>
#include <math.h>

#define IMG 224
#define NPIX 50176
#define BATCH 64
#define EDIM 256

typedef __bf16 bf16;
typedef __attribute__((ext_vector_type(8))) __bf16 bf16x8;
typedef __attribute__((ext_vector_type(4))) float f32x4;
typedef unsigned short u16;
typedef unsigned int u32;

// GEMM geometry: block 64(M) x 128(N), BK=64, 256 threads = 4 waves (2x2),
// wave tile 32x64 = 2x4 frags of 16x16, mfma_f32_16x16x32_bf16.
// A layout [M][LDK] k-contiguous; B layout [N][LDK] k-contiguous (TN gemm).
// M_A = 64*224 = 14336, KP_A = 256 (224 valid), N_A = 256 (226 valid)
// M_B = 448 (rows 2u=re,2u+1=im), KP_B = 512 (Yr @ k=h, Yi @ k=256+h), N_B = 7296 (7232 valid)

__device__ __forceinline__ u16 f2bf(float f) {
  u32 u = __builtin_bit_cast(u32, f);
  u += 0x7fffu + ((u >> 16) & 1u);
  return (u16)(u >> 16);
}
__device__ __forceinline__ float bf2f(u16 s) {
  u32 u = ((u32)s) << 16;
  return __builtin_bit_cast(float, u);
}

#define GLD16(gp, lp)                                                          \
  __builtin_amdgcn_global_load_lds(                                            \
      (const __attribute__((address_space(1))) u32*)(gp),                      \
      (__attribute__((address_space(3))) u32*)(lp), 16, 0, 0)

// ---- shared GEMM core (3-pass split-bf16 accumulate) ---------------------
template <int LDK>
__device__ __forceinline__ void gemm_core(const bf16* __restrict__ Ah,
                                          const bf16* __restrict__ Al,
                                          const bf16* __restrict__ Bh,
                                          const bf16* __restrict__ Bl,
                                          int m0, int n0,
                                          bf16 (*As)[64], bf16 (*Bs)[64],
                                          f32x4 acc[2][4]) {
  int tid = threadIdx.x;
  int lane = tid & 63, wid = tid >> 6;
  int wr = wid >> 1, wc = wid & 1;
  int srow = lane >> 3;                    // 0..7 row within 8-row chunk
  int sslot = lane & 7;                    // physical 16B slot in 128B row
  int sk8 = sslot ^ (srow & 7);            // logical slot (XOR swizzle, involution)

#pragma unroll 1
  for (int pass = 0; pass < 3; ++pass) {
    const bf16* Ap = (pass == 2) ? Al : Ah;
    const bf16* Bp = (pass == 1) ? Bl : Bh;
#pragma unroll 1
    for (int k0 = 0; k0 < LDK; k0 += 64) {
      // stage 24 KB: A 8 chunks (64 rows), B 16 chunks (128 rows); 6 per wave
#pragma unroll
      for (int ci = 0; ci < 6; ++ci) {
        int c = wid * 6 + ci;
        if (c < 8) {
          int row = c * 8 + srow;
          GLD16(Ap + (size_t)(m0 + row) * LDK + k0 + sk8 * 8,
                &As[0][0] + c * 512);
        } else {
          int j = c - 8;
          int row = j * 8 + srow;
          GLD16(Bp + (size_t)(n0 + row) * LDK + k0 + sk8 * 8,
                &Bs[0][0] + j * 512);
        }
      }
      __syncthreads();
#pragma unroll
      for (int kk = 0; kk < 2; ++kk) {
        bf16x8 af[2], bfr[4];
#pragma unroll
        for (int mi = 0; mi < 2; ++mi) {
          int row = wr * 32 + mi * 16 + (lane & 15);
          int slot = (kk * 4 + (lane >> 4)) ^ (row & 7);
          af[mi] = *(const bf16x8*)&As[row][slot * 8];
        }
#pragma unroll
        for (int nj = 0; nj < 4; ++nj) {
          int row = wc * 64 + nj * 16 + (lane & 15);
          int slot = (kk * 4 + (lane >> 4)) ^ (row & 7);
          bfr[nj] = *(const bf16x8*)&Bs[row][slot * 8];
        }
#pragma unroll
        for (int mi = 0; mi < 2; ++mi)
#pragma unroll
          for (int nj = 0; nj < 4; ++nj)
            acc[mi][nj] = __builtin_amdgcn_mfma_f32_16x16x32_bf16(
                af[mi], bfr[nj], acc[mi][nj], 0, 0, 0);
      }
      __syncthreads();
    }
  }
}

// ---- stage A: Y = gray * B1t^T; epilogue writes split-bf16 B2t ------------
__global__ __launch_bounds__(256) void gemmA_kernel(const bf16* __restrict__ Gh,
                                                    const bf16* __restrict__ Gl,
                                                    const bf16* __restrict__ B1h,
                                                    const bf16* __restrict__ B1l,
                                                    u16* __restrict__ B2th,
                                                    u16* __restrict__ B2tl) {
  __shared__ bf16 As[64][64];
  __shared__ bf16 Bs[128][64];
  int m0 = blockIdx.y * 64, n0 = blockIdx.x * 128;
  f32x4 acc[2][4];
#pragma unroll
  for (int i = 0; i < 2; ++i)
#pragma unroll
    for (int j = 0; j < 4; ++j) acc[i][j] = (f32x4){0.f, 0.f, 0.f, 0.f};

  gemm_core<256>(Gh, Gl, B1h, B1l, m0, n0, As, Bs, acc);

  int lane = threadIdx.x & 63, wid = threadIdx.x >> 6;
  int wr = wid >> 1, wc = wid & 1;
  int mbase = m0 + wr * 32, nbase = n0 + wc * 64;
#pragma unroll
  for (int mi = 0; mi < 2; ++mi) {
#pragma unroll
    for (int nj = 0; nj < 4; ++nj) {
      int c = nbase + nj * 16 + (lane & 15);
      if (c >= 226) continue;
      int m = mbase + mi * 16 + ((lane >> 4) << 2);  // 4 consecutive rows, m%4==0
      int b = m / 224;
      int h = m - b * 224;                           // h%4==0 -> no batch wrap
      int v = c, kb = h;
      if (c >= 113) { v = c - 113; kb = 256 + h; }
      size_t off = (size_t)(b * 113 + v) * 512 + kb;
      f32x4 y = acc[mi][nj];
      u16 hs[4], ls[4];
#pragma unroll
      for (int r = 0; r < 4; ++r) {
        float f = y[r];
        u16 hb = f2bf(f);
        hs[r] = hb;
        ls[r] = f2bf(f - bf2f(hb));
      }
      *(ushort4*)&B2th[off] = make_ushort4(hs[0], hs[1], hs[2], hs[3]);
      *(ushort4*)&B2tl[off] = make_ushort4(ls[0], ls[1], ls[2], ls[3]);
    }
  }
}

// ---- stage B: F = W2 * B2t^T; fused log1p(|F|) + fftshift + mirror --------
__global__ __launch_bounds__(256) void gemmB_kernel(const bf16* __restrict__ W2h,
                                                    const bf16* __restrict__ W2l,
                                                    const bf16* __restrict__ B2h,
                                                    const bf16* __restrict__ B2l,
                                                    float* __restrict__ mag) {
  __shared__ bf16 As[64][64];
  __shared__ bf16 Bs[128][64];
  int m0 = blockIdx.y * 64, n0 = blockIdx.x * 128;
  f32x4 acc[2][4];
#pragma unroll
  for (int i = 0; i < 2; ++i)
#pragma unroll
    for (int j = 0; j < 4; ++j) acc[i][j] = (f32x4){0.f, 0.f, 0.f, 0.f};

  gemm_core<512>(W2h, W2l, B2h, B2l, m0, n0, As, Bs, acc);

  int lane = threadIdx.x & 63, wid = threadIdx.x >> 6;
  int wr = wid >> 1, wc = wid & 1;
  int rbase = m0 + wr * 32, nbase = n0 + wc * 64;
#pragma unroll
  for (int mi = 0; mi < 2; ++mi) {
#pragma unroll
    for (int nj = 0; nj < 4; ++nj) {
      int n = nbase + nj * 16 + (lane & 15);
      if (n >= 7232) continue;
      int b = n / 113;
      int v = n - b * 113;                 // 0..112
      int rr = rbase + mi * 16 + ((lane >> 4) << 2);  // rr%4==0, rr<448
      int u0 = rr >> 1;
      f32x4 f = acc[mi][nj];
      float* magb = mag + (size_t)b * NPIX;
#pragma unroll
      for (int p = 0; p < 2; ++p) {
        float re = f[2 * p], im = f[2 * p + 1];
        int u = u0 + p;
        float mv = log1pf(sqrtf(re * re + im * im));
        int us = u + 112; if (us >= 224) us -= 224;
        int vs = v + 112; if (vs >= 224) vs -= 224;
        magb[us * IMG + vs] = mv;
        int u2 = (u == 0) ? 0 : 224 - u;
        int v2 = (v == 0) ? 0 : 224 - v;
        int us2 = u2 + 112; if (us2 >= 224) us2 -= 224;
        int vs2 = v2 + 112; if (vs2 >= 224) vs2 -= 224;
        magb[us2 * IMG + vs2] = mv;
      }
    }
  }
}

// ---- prep kernels ---------------------------------------------------------
__global__ __launch_bounds__(256) void gray_split_kernel(const float* __restrict__ x,
                                                         u16* __restrict__ Gh,
                                                         u16* __restrict__ Gl) {
  int m = blockIdx.x;        // 0..14335 = b*224 + h
  int k = threadIdx.x;       // 0..255
  float g = 0.f;
  if (k < 224) {
    int b = m / 224, h = m - b * 224;
    const float* xb = x + (size_t)b * 3 * NPIX + h * IMG + k;
    g = (xb[0] + xb[NPIX] + xb[2 * NPIX]) * (1.0f / 3.0f);
  }
  u16 hb = f2bf(g);
  Gh[(size_t)m * 256 + k] = hb;
  Gl[(size_t)m * 256 + k] = f2bf(g - bf2f(hb));
}

__global__ __launch_bounds__(256) void b1t_kernel(u16* __restrict__ B1h,
                                                  u16* __restrict__ B1l) {
  int n = blockIdx.x;        // 0..255
  int k = threadIdx.x;       // 0..255 (w)
  float val = 0.f;
  if (k < 224 && n < 226) {
    int v = (n < 113) ? n : n - 113;
    int m = (k * v) % 224;
    double ang = -2.0 * 3.14159265358979323846 * (double)m / 224.0;
    val = (n < 113) ? (float)cos(ang) : (float)sin(ang);  // cos(th) / -sin(th)
  }
  u16 hb = f2bf(val);
  B1h[n * 256 + k] = hb;
  B1l[n * 256 + k] = f2bf(val - bf2f(hb));
}

__global__ __launch_bounds__(256) void w2_kernel(u16* __restrict__ W2h,
                                                 u16* __restrict__ W2l) {
  int row = blockIdx.x >> 1;                       // 0..447
  int k = ((blockIdx.x & 1) << 8) + threadIdx.x;   // 0..511
  int u = row >> 1;
  bool imrow = row & 1;
  bool kim = k >= 256;
  int kk = kim ? k - 256 : k;
  float val = 0.f;
  if (kk < 224) {
    int m = (u * kk) % 224;
    double th = 2.0 * 3.14159265358979323846 * (double)m / 224.0;
    double c = cos(th), s = sin(th);
    // F_re = cos*Yr + sin*Yi ; F_im = -sin*Yr + cos*Yi
    val = imrow ? (kim ? (float)c : (float)(-s)) : (kim ? (float)s : (float)c);
  }
  u16 hb = f2bf(val);
  W2h[row * 512 + k] = hb;
  W2l[row * 512 + k] = f2bf(val - bf2f(hb));
}

__global__ __launch_bounds__(256) void zero16_kernel(u32* __restrict__ p) {
  size_t i = ((size_t)blockIdx.x * 256 + threadIdx.x) * 4;
  p[i] = 0; p[i + 1] = 0; p[i + 2] = 0; p[i + 3] = 0;
}

__global__ __launch_bounds__(256) void band_kernel(unsigned char* __restrict__ band) {
  int p = blockIdx.x * 256 + threadIdx.x;
  int u = p / IMG, v = p % IMG;
  int dx = v - 112, dy = u - 112;
  float r = sqrtf((float)(dx * dx + dy * dy));
  float step = (float)(158.39191898578665 / 8.0);
  unsigned char bd = 255;
#pragma unroll
  for (int k = 0; k < 8; k++) {
    float lo = step * (float)k;
    float hi = step * (float)(k + 1);
    if (r >= lo && r < hi) bd = (unsigned char)k;
  }
  band[p] = bd;
}

// ---- per-image stats ------------------------------------------------------
__global__ __launch_bounds__(256) void stats_kernel(const float* __restrict__ mag,
                                                    const unsigned char* __restrict__ band,
                                                    float* __restrict__ stats) {
  int b = blockIdx.x;
  int tid = threadIdx.x;
  const float* mb = mag + (size_t)b * NPIX;
  float gsum = 0.0f, gsq = 0.0f;
  float s1[8] = {0}, s2[8] = {0}, cnt[8] = {0}, mx[8];
#pragma unroll
  for (int k = 0; k < 8; k++) mx[k] = -1e30f;

  for (int p = tid; p < NPIX; p += 256) {
    float v = mb[p];
    int bt = band[p];
    gsum += v;
    gsq += v * v;
#pragma unroll
    for (int k = 0; k < 8; k++) {
      bool m = (bt == k);
      s1[k] += m ? v : 0.0f;
      s2[k] += m ? v * v : 0.0f;
      cnt[k] += m ? 1.0f : 0.0f;
      mx[k] = m ? fmaxf(mx[k], v) : mx[k];
    }
  }

  float vals[34];
  vals[0] = gsum; vals[1] = gsq;
#pragma unroll
  for (int k = 0; k < 8; k++) {
    vals[2 + k] = s1[k]; vals[10 + k] = s2[k]; vals[18 + k] = mx[k]; vals[26 + k] = cnt[k];
  }
#pragma unroll
  for (int i = 0; i < 34; i++) {
    float v = vals[i];
    const bool isMax = (i >= 18 && i < 26);
#pragma unroll
    for (int off = 32; off > 0; off >>= 1) {
      float o = __shfl_down(v, off);
      v = isMax ? fmaxf(v, o) : (v + o);
    }
    vals[i] = v;
  }
  __shared__ float red[4][34];
  int w = tid >> 6;
  if ((tid & 63) == 0) {
#pragma unroll
    for (int i = 0; i < 34; i++) red[w][i] = vals[i];
  }
  __syncthreads();
  if (tid < 34) {
    bool isMax = (tid >= 18 && tid < 26);
    float v = red[0][tid];
    for (int ww = 1; ww < 4; ww++) v = isMax ? fmaxf(v, red[ww][tid]) : (v + red[ww][tid]);
    stats[b * 34 + tid] = v;
  }
}

// ---- MLP ------------------------------------------------------------------
__global__ __launch_bounds__(256) void mlp_kernel(const float* __restrict__ stats,
                                                  const float* __restrict__ W1,
                                                  const float* __restrict__ b1,
                                                  const float* __restrict__ gamma,
                                                  const float* __restrict__ beta,
                                                  const float* __restrict__ W2m,
                                                  const float* __restrict__ b2,
                                                  float* __restrict__ out) {
  int bk = blockIdx.x;
  int b = bk >> 3, k = bk & 7;
  int e = threadIdx.x;
  const float* st = stats + b * 34;
  const float N = (float)NPIX;

  float mu = st[0] / N;
  float varg = fmaxf(st[1] - N * mu * mu, 0.0f) / (N - 1.0f);
  float sd = sqrtf(varg) + 1e-6f;

  float s1r = st[2 + k], s2r = st[10 + k], mxr = st[18 + k], cntk = st[26 + k];
  float ms = cntk + 1e-6f;
  float s1n = (s1r - mu * cntk) / sd;
  float s2n = (s2r - 2.0f * mu * s1r + mu * mu * cntk) / (sd * sd);
  float mean_k = s1n / ms;
  float var_num = s2n - 2.0f * mean_k * s1n + mean_k * mean_k * cntk;
  float std_k = sqrtf(var_num / ms + 1e-6f);
  float max_k = (mxr - mu) / sd;

  float h = mean_k * W1[e] + std_k * W1[EDIM + e] + max_k * W1[2 * EDIM + e] + b1[e];

  float s = h, q = h * h;
#pragma unroll
  for (int off = 32; off > 0; off >>= 1) {
    s += __shfl_down(s, off);
    q += __shfl_down(q, off);
  }
  __shared__ float rs[4], rq[4];
  __shared__ float hmS, hvS;
  if ((e & 63) == 0) { rs[e >> 6] = s; rq[e >> 6] = q; }
  __syncthreads();
  if (e == 0) {
    float ts = rs[0] + rs[1] + rs[2] + rs[3];
    float tq = rq[0] + rq[1] + rq[2] + rq[3];
    float hm = ts / 256.0f;
    hmS = hm;
    hvS = fmaxf(tq / 256.0f - hm * hm, 0.0f);
  }
  __syncthreads();
  float hn = (h - hmS) / sqrtf(hvS + 1e-5f) * gamma[e] + beta[e];
  float hr = fmaxf(hn, 0.0f);

  __shared__ float hs[EDIM];
  hs[e] = hr;
  __syncthreads();

  float acc = b2[e];
#pragma unroll 8
  for (int j = 0; j < EDIM; j++) acc += hs[j] * W2m[j * EDIM + e];
  out[(size_t)bk * EDIM + e] = acc;
}

// ---- launch ---------------------------------------------------------------
extern "C" void kernel_launch(void* const* d_in, const int* in_sizes, int n_in,
                              void* d_out, int out_size, void* d_ws, size_t ws_size,
                              hipStream_t stream) {
  const float* x     = (const float*)d_in[0];
  const float* W1    = (const float*)d_in[1];
  const float* b1    = (const float*)d_in[2];
  const float* gamma = (const float*)d_in[3];
  const float* beta  = (const float*)d_in[4];
  const float* W2m   = (const float*)d_in[5];
  const float* b2    = (const float*)d_in[6];
  float* out = (float*)d_out;

  char* W = (char*)d_ws;
  // R1: Gh, Gl (7,340,032 B each) -- later aliased by mag (12,845,056 B)
  u16* Gh = (u16*)W;
  u16* Gl = Gh + (size_t)14336 * 256;
  float* mag = (float*)W;
  // R2: B2t planes (7,471,104 B each)
  const size_t R2 = 14680064;
  u16* B2th = (u16*)(W + R2);
  u16* B2tl = B2th + (size_t)7296 * 512;
  // R3: small tables
  const size_t R3 = R2 + 14942208;
  u16* B1h = (u16*)(W + R3);
  u16* B1l = B1h + 65536;
  u16* W2h = B1l + 65536;
  u16* W2l = W2h + (size_t)448 * 512;
  unsigned char* band = (unsigned char*)(W2l + (size_t)448 * 512);
  float* stats = (float*)(band + NPIX);

  gray_split_kernel<<<dim3(14336), dim3(256), 0, stream>>>(x, Gh, Gl);
  b1t_kernel<<<dim3(256), dim3(256), 0, stream>>>(B1h, B1l);
  w2_kernel<<<dim3(896), dim3(256), 0, stream>>>(W2h, W2l);
  zero16_kernel<<<dim3(3648), dim3(256), 0, stream>>>((u32*)B2th);  // zeros B2th+B2tl
  band_kernel<<<dim3(NPIX / 256), dim3(256), 0, stream>>>(band);

  gemmA_kernel<<<dim3(2, 224), dim3(256), 0, stream>>>(
      (const bf16*)Gh, (const bf16*)Gl, (const bf16*)B1h, (const bf16*)B1l, B2th, B2tl);
  gemmB_kernel<<<dim3(57, 7), dim3(256), 0, stream>>>(
      (const bf16*)W2h, (const bf16*)W2l, (const bf16*)B2th, (const bf16*)B2tl, mag);

  stats_kernel<<<dim3(BATCH), dim3(256), 0, stream>>>(mag, band, stats);
  mlp_kernel<<<dim3(BATCH * 8), dim3(256), 0, stream>>>(stats, W1, b1, gamma, beta, W2m, b2, out);
}

// Round 3
// 108.113 us; speedup vs baseline: 4.3882x; 1.5988x over previous
//
#include <hip/hip_runtime.h>
#include <math.h>

#define IMG 224
#define NPIX 50176
#define BATCH 64
#define EDIM 256
#define NCHUNK 28
#define CHUNKPIX 1792

typedef __bf16 bf16;
typedef __attribute__((ext_vector_type(8))) __bf16 bf16x8;
typedef __attribute__((ext_vector_type(4))) float f32x4;
typedef unsigned short u16;
typedef unsigned int u32;

// GEMM geometry: block 64(M) x 128(N), BK=64, 256 threads = 4 waves (2x2),
// wave tile 32x64 = 2x4 frags of 16x16, mfma_f32_16x16x32_bf16.
// A layout [M][LDK] k-contiguous; B layout [N][LDK] k-contiguous (TN gemm).

__device__ __forceinline__ u16 f2bf(float f) {
  u32 u = __builtin_bit_cast(u32, f);
  u += 0x7fffu + ((u >> 16) & 1u);
  return (u16)(u >> 16);
}
__device__ __forceinline__ float bf2f(u16 s) {
  u32 u = ((u32)s) << 16;
  return __builtin_bit_cast(float, u);
}

#define GLD16(gp, lp)                                                          \
  __builtin_amdgcn_global_load_lds(                                            \
      (const __attribute__((address_space(1))) u32*)(gp),                      \
      (__attribute__((address_space(3))) u32*)(lp), 16, 0, 0)

// ---- shared GEMM core (3-pass split-bf16 accumulate) ---------------------
template <int LDK>
__device__ __forceinline__ void gemm_core(const bf16* __restrict__ Ah,
                                          const bf16* __restrict__ Al,
                                          const bf16* __restrict__ Bh,
                                          const bf16* __restrict__ Bl,
                                          int m0, int n0,
                                          bf16 (*As)[64], bf16 (*Bs)[64],
                                          f32x4 acc[2][4]) {
  int tid = threadIdx.x;
  int lane = tid & 63, wid = tid >> 6;
  int wr = wid >> 1, wc = wid & 1;
  int srow = lane >> 3;
  int sslot = lane & 7;
  int sk8 = sslot ^ (srow & 7);

#pragma unroll 1
  for (int pass = 0; pass < 3; ++pass) {
    const bf16* Ap = (pass == 2) ? Al : Ah;
    const bf16* Bp = (pass == 1) ? Bl : Bh;
#pragma unroll 1
    for (int k0 = 0; k0 < LDK; k0 += 64) {
#pragma unroll
      for (int ci = 0; ci < 6; ++ci) {
        int c = wid * 6 + ci;
        if (c < 8) {
          int row = c * 8 + srow;
          GLD16(Ap + (size_t)(m0 + row) * LDK + k0 + sk8 * 8,
                &As[0][0] + c * 512);
        } else {
          int j = c - 8;
          int row = j * 8 + srow;
          GLD16(Bp + (size_t)(n0 + row) * LDK + k0 + sk8 * 8,
                &Bs[0][0] + j * 512);
        }
      }
      __syncthreads();
#pragma unroll
      for (int kk = 0; kk < 2; ++kk) {
        bf16x8 af[2], bfr[4];
#pragma unroll
        for (int mi = 0; mi < 2; ++mi) {
          int row = wr * 32 + mi * 16 + (lane & 15);
          int slot = (kk * 4 + (lane >> 4)) ^ (row & 7);
          af[mi] = *(const bf16x8*)&As[row][slot * 8];
        }
#pragma unroll
        for (int nj = 0; nj < 4; ++nj) {
          int row = wc * 64 + nj * 16 + (lane & 15);
          int slot = (kk * 4 + (lane >> 4)) ^ (row & 7);
          bfr[nj] = *(const bf16x8*)&Bs[row][slot * 8];
        }
#pragma unroll
        for (int mi = 0; mi < 2; ++mi)
#pragma unroll
          for (int nj = 0; nj < 4; ++nj)
            acc[mi][nj] = __builtin_amdgcn_mfma_f32_16x16x32_bf16(
                af[mi], bfr[nj], acc[mi][nj], 0, 0, 0);
      }
      __syncthreads();
    }
  }
}

// ---- stage A: Y = gray * B1t^T; epilogue writes split-bf16 B2t ------------
__global__ __launch_bounds__(256) void gemmA_kernel(const bf16* __restrict__ Gh,
                                                    const bf16* __restrict__ Gl,
                                                    const bf16* __restrict__ B1h,
                                                    const bf16* __restrict__ B1l,
                                                    u16* __restrict__ B2th,
                                                    u16* __restrict__ B2tl) {
  __shared__ bf16 As[64][64];
  __shared__ bf16 Bs[128][64];
  int m0 = blockIdx.y * 64, n0 = blockIdx.x * 128;
  f32x4 acc[2][4];
#pragma unroll
  for (int i = 0; i < 2; ++i)
#pragma unroll
    for (int j = 0; j < 4; ++j) acc[i][j] = (f32x4){0.f, 0.f, 0.f, 0.f};

  gemm_core<256>(Gh, Gl, B1h, B1l, m0, n0, As, Bs, acc);

  int lane = threadIdx.x & 63, wid = threadIdx.x >> 6;
  int wr = wid >> 1, wc = wid & 1;
  int mbase = m0 + wr * 32, nbase = n0 + wc * 64;
#pragma unroll
  for (int mi = 0; mi < 2; ++mi) {
#pragma unroll
    for (int nj = 0; nj < 4; ++nj) {
      int c = nbase + nj * 16 + (lane & 15);
      if (c >= 226) continue;
      int m = mbase + mi * 16 + ((lane >> 4) << 2);
      int b = m / 224;
      int h = m - b * 224;
      int v = c, kb = h;
      if (c >= 113) { v = c - 113; kb = 256 + h; }
      size_t off = (size_t)(b * 113 + v) * 512 + kb;
      f32x4 y = acc[mi][nj];
      u16 hs[4], ls[4];
#pragma unroll
      for (int r = 0; r < 4; ++r) {
        float f = y[r];
        u16 hb = f2bf(f);
        hs[r] = hb;
        ls[r] = f2bf(f - bf2f(hb));
      }
      *(ushort4*)&B2th[off] = make_ushort4(hs[0], hs[1], hs[2], hs[3]);
      *(ushort4*)&B2tl[off] = make_ushort4(ls[0], ls[1], ls[2], ls[3]);
    }
  }
}

// ---- stage B: F = W2 * B2t^T; fused log1p(|F|) + fftshift + mirror --------
__global__ __launch_bounds__(256) void gemmB_kernel(const bf16* __restrict__ W2h,
                                                    const bf16* __restrict__ W2l,
                                                    const bf16* __restrict__ B2h,
                                                    const bf16* __restrict__ B2l,
                                                    float* __restrict__ mag) {
  __shared__ bf16 As[64][64];
  __shared__ bf16 Bs[128][64];
  int m0 = blockIdx.y * 64, n0 = blockIdx.x * 128;
  f32x4 acc[2][4];
#pragma unroll
  for (int i = 0; i < 2; ++i)
#pragma unroll
    for (int j = 0; j < 4; ++j) acc[i][j] = (f32x4){0.f, 0.f, 0.f, 0.f};

  gemm_core<512>(W2h, W2l, B2h, B2l, m0, n0, As, Bs, acc);

  int lane = threadIdx.x & 63, wid = threadIdx.x >> 6;
  int wr = wid >> 1, wc = wid & 1;
  int rbase = m0 + wr * 32, nbase = n0 + wc * 64;
#pragma unroll
  for (int mi = 0; mi < 2; ++mi) {
#pragma unroll
    for (int nj = 0; nj < 4; ++nj) {
      int n = nbase + nj * 16 + (lane & 15);
      if (n >= 7232) continue;
      int b = n / 113;
      int v = n - b * 113;
      int rr = rbase + mi * 16 + ((lane >> 4) << 2);
      int u0 = rr >> 1;
      f32x4 f = acc[mi][nj];
      float* magb = mag + (size_t)b * NPIX;
#pragma unroll
      for (int p = 0; p < 2; ++p) {
        float re = f[2 * p], im = f[2 * p + 1];
        int u = u0 + p;
        float mv = log1pf(sqrtf(re * re + im * im));
        int us = u + 112; if (us >= 224) us -= 224;
        int vs = v + 112; if (vs >= 224) vs -= 224;
        magb[us * IMG + vs] = mv;
        int u2 = (u == 0) ? 0 : 224 - u;
        int v2 = (v == 0) ? 0 : 224 - v;
        int us2 = u2 + 112; if (us2 >= 224) us2 -= 224;
        int vs2 = v2 + 112; if (vs2 >= 224) vs2 -= 224;
        magb[us2 * IMG + vs2] = mv;
      }
    }
  }
}

// ---- prep kernels ---------------------------------------------------------
__global__ __launch_bounds__(256) void gray_split_kernel(const float* __restrict__ x,
                                                         u16* __restrict__ Gh,
                                                         u16* __restrict__ Gl) {
  int m = blockIdx.x;
  int k = threadIdx.x;
  float g = 0.f;
  if (k < 224) {
    int b = m / 224, h = m - b * 224;
    const float* xb = x + (size_t)b * 3 * NPIX + h * IMG + k;
    g = (xb[0] + xb[NPIX] + xb[2 * NPIX]) * (1.0f / 3.0f);
  }
  u16 hb = f2bf(g);
  Gh[(size_t)m * 256 + k] = hb;
  Gl[(size_t)m * 256 + k] = f2bf(g - bf2f(hb));
}

__global__ __launch_bounds__(256) void b1t_kernel(u16* __restrict__ B1h,
                                                  u16* __restrict__ B1l) {
  int n = blockIdx.x;
  int k = threadIdx.x;
  float val = 0.f;
  if (k < 224 && n < 226) {
    int v = (n < 113) ? n : n - 113;
    int m = (k * v) % 224;
    double ang = -2.0 * 3.14159265358979323846 * (double)m / 224.0;
    val = (n < 113) ? (float)cos(ang) : (float)sin(ang);
  }
  u16 hb = f2bf(val);
  B1h[n * 256 + k] = hb;
  B1l[n * 256 + k] = f2bf(val - bf2f(hb));
}

__global__ __launch_bounds__(256) void w2_kernel(u16* __restrict__ W2h,
                                                 u16* __restrict__ W2l) {
  int row = blockIdx.x >> 1;
  int k = ((blockIdx.x & 1) << 8) + threadIdx.x;
  int u = row >> 1;
  bool imrow = row & 1;
  bool kim = k >= 256;
  int kk = kim ? k - 256 : k;
  float val = 0.f;
  if (kk < 224) {
    int m = (u * kk) % 224;
    double th = 2.0 * 3.14159265358979323846 * (double)m / 224.0;
    double c = cos(th), s = sin(th);
    val = imrow ? (kim ? (float)c : (float)(-s)) : (kim ? (float)s : (float)c);
  }
  u16 hb = f2bf(val);
  W2h[row * 512 + k] = hb;
  W2l[row * 512 + k] = f2bf(val - bf2f(hb));
}

__global__ __launch_bounds__(256) void zero16_kernel(u32* __restrict__ p) {
  size_t i = ((size_t)blockIdx.x * 256 + threadIdx.x) * 4;
  p[i] = 0; p[i + 1] = 0; p[i + 2] = 0; p[i + 3] = 0;
}

__global__ __launch_bounds__(256) void band_kernel(unsigned char* __restrict__ band) {
  int p = blockIdx.x * 256 + threadIdx.x;
  int u = p / IMG, v = p % IMG;
  int dx = v - 112, dy = u - 112;
  float r = sqrtf((float)(dx * dx + dy * dy));
  float step = (float)(158.39191898578665 / 8.0);
  unsigned char bd = 255;
#pragma unroll
  for (int k = 0; k < 8; k++) {
    float lo = step * (float)k;
    float hi = step * (float)(k + 1);
    if (r >= lo && r < hi) bd = (unsigned char)k;
  }
  band[p] = bd;
}

// ---- two-stage per-image stats -------------------------------------------
// layout: [0]=gsum [1]=gsumsq [2+k]=s1 [10+k]=s2 [18+k]=max [26+k]=count
__global__ __launch_bounds__(256) void stats_partial_kernel(
    const float* __restrict__ mag, const unsigned char* __restrict__ band,
    float* __restrict__ part) {
  int chunk = blockIdx.x;   // 0..27
  int b = blockIdx.y;       // 0..63
  int tid = threadIdx.x;
  const float* mb = mag + (size_t)b * NPIX + chunk * CHUNKPIX;
  const unsigned char* bb = band + chunk * CHUNKPIX;

  float gsum = 0.0f, gsq = 0.0f;
  float s1[8] = {0}, s2[8] = {0}, cnt[8] = {0}, mx[8];
#pragma unroll
  for (int k = 0; k < 8; k++) mx[k] = -1e30f;

#pragma unroll
  for (int i = 0; i < 7; i++) {   // 7*256 = 1792 pixels
    int p = i * 256 + tid;
    float v = mb[p];
    int bt = bb[p];
    gsum += v;
    gsq += v * v;
#pragma unroll
    for (int k = 0; k < 8; k++) {
      bool m = (bt == k);
      s1[k] += m ? v : 0.0f;
      s2[k] += m ? v * v : 0.0f;
      cnt[k] += m ? 1.0f : 0.0f;
      mx[k] = m ? fmaxf(mx[k], v) : mx[k];
    }
  }

  float vals[34];
  vals[0] = gsum; vals[1] = gsq;
#pragma unroll
  for (int k = 0; k < 8; k++) {
    vals[2 + k] = s1[k]; vals[10 + k] = s2[k]; vals[18 + k] = mx[k]; vals[26 + k] = cnt[k];
  }
#pragma unroll
  for (int i = 0; i < 34; i++) {
    float v = vals[i];
    const bool isMax = (i >= 18 && i < 26);
#pragma unroll
    for (int off = 32; off > 0; off >>= 1) {
      float o = __shfl_down(v, off);
      v = isMax ? fmaxf(v, o) : (v + o);
    }
    vals[i] = v;
  }
  __shared__ float red[4][34];
  int w = tid >> 6;
  if ((tid & 63) == 0) {
#pragma unroll
    for (int i = 0; i < 34; i++) red[w][i] = vals[i];
  }
  __syncthreads();
  if (tid < 34) {
    bool isMax = (tid >= 18 && tid < 26);
    float v = red[0][tid];
    for (int ww = 1; ww < 4; ww++) v = isMax ? fmaxf(v, red[ww][tid]) : (v + red[ww][tid]);
    part[((size_t)b * NCHUNK + chunk) * 34 + tid] = v;
  }
}

__global__ __launch_bounds__(64) void stats_final_kernel(const float* __restrict__ part,
                                                         float* __restrict__ stats) {
  int b = blockIdx.x;
  int t = threadIdx.x;
  if (t >= 34) return;
  bool isMax = (t >= 18 && t < 26);
  const float* pb = part + (size_t)b * NCHUNK * 34;
  float v = pb[t];
#pragma unroll
  for (int c = 1; c < NCHUNK; c++) {
    float o = pb[c * 34 + t];
    v = isMax ? fmaxf(v, o) : (v + o);
  }
  stats[b * 34 + t] = v;
}

// ---- MLP ------------------------------------------------------------------
__global__ __launch_bounds__(256) void mlp_kernel(const float* __restrict__ stats,
                                                  const float* __restrict__ W1,
                                                  const float* __restrict__ b1,
                                                  const float* __restrict__ gamma,
                                                  const float* __restrict__ beta,
                                                  const float* __restrict__ W2m,
                                                  const float* __restrict__ b2,
                                                  float* __restrict__ out) {
  int bk = blockIdx.x;
  int b = bk >> 3, k = bk & 7;
  int e = threadIdx.x;
  const float* st = stats + b * 34;
  const float N = (float)NPIX;

  float mu = st[0] / N;
  float varg = fmaxf(st[1] - N * mu * mu, 0.0f) / (N - 1.0f);
  float sd = sqrtf(varg) + 1e-6f;

  float s1r = st[2 + k], s2r = st[10 + k], mxr = st[18 + k], cntk = st[26 + k];
  float ms = cntk + 1e-6f;
  float s1n = (s1r - mu * cntk) / sd;
  float s2n = (s2r - 2.0f * mu * s1r + mu * mu * cntk) / (sd * sd);
  float mean_k = s1n / ms;
  float var_num = s2n - 2.0f * mean_k * s1n + mean_k * mean_k * cntk;
  float std_k = sqrtf(var_num / ms + 1e-6f);
  float max_k = (mxr - mu) / sd;

  float h = mean_k * W1[e] + std_k * W1[EDIM + e] + max_k * W1[2 * EDIM + e] + b1[e];

  float s = h, q = h * h;
#pragma unroll
  for (int off = 32; off > 0; off >>= 1) {
    s += __shfl_down(s, off);
    q += __shfl_down(q, off);
  }
  __shared__ float rs[4], rq[4];
  __shared__ float hmS, hvS;
  if ((e & 63) == 0) { rs[e >> 6] = s; rq[e >> 6] = q; }
  __syncthreads();
  if (e == 0) {
    float ts = rs[0] + rs[1] + rs[2] + rs[3];
    float tq = rq[0] + rq[1] + rq[2] + rq[3];
    float hm = ts / 256.0f;
    hmS = hm;
    hvS = fmaxf(tq / 256.0f - hm * hm, 0.0f);
  }
  __syncthreads();
  float hn = (h - hmS) / sqrtf(hvS + 1e-5f) * gamma[e] + beta[e];
  float hr = fmaxf(hn, 0.0f);

  __shared__ float hs[EDIM];
  hs[e] = hr;
  __syncthreads();

  float acc = b2[e];
#pragma unroll 8
  for (int j = 0; j < EDIM; j++) acc += hs[j] * W2m[j * EDIM + e];
  out[(size_t)bk * EDIM + e] = acc;
}

// ---- launch ---------------------------------------------------------------
extern "C" void kernel_launch(void* const* d_in, const int* in_sizes, int n_in,
                              void* d_out, int out_size, void* d_ws, size_t ws_size,
                              hipStream_t stream) {
  const float* x     = (const float*)d_in[0];
  const float* W1    = (const float*)d_in[1];
  const float* b1    = (const float*)d_in[2];
  const float* gamma = (const float*)d_in[3];
  const float* beta  = (const float*)d_in[4];
  const float* W2m   = (const float*)d_in[5];
  const float* b2    = (const float*)d_in[6];
  float* out = (float*)d_out;

  char* W = (char*)d_ws;
  // R1: Gh, Gl (7,340,032 B each) -- later aliased by mag (12,845,056 B)
  u16* Gh = (u16*)W;
  u16* Gl = Gh + (size_t)14336 * 256;
  float* mag = (float*)W;
  // R2: B2t planes (7,471,104 B each)
  const size_t R2 = 14680064;
  u16* B2th = (u16*)(W + R2);
  u16* B2tl = B2th + (size_t)7296 * 512;
  // R3: small tables
  const size_t R3 = R2 + 14942208;
  u16* B1h = (u16*)(W + R3);
  u16* B1l = B1h + 65536;
  u16* W2h = B1l + 65536;
  u16* W2l = W2h + (size_t)448 * 512;
  unsigned char* band = (unsigned char*)(W2l + (size_t)448 * 512);
  float* stats = (float*)(band + NPIX);
  float* part = stats + BATCH * 34;   // 64*28*34 floats = 243,712 B

  gray_split_kernel<<<dim3(14336), dim3(256), 0, stream>>>(x, Gh, Gl);
  b1t_kernel<<<dim3(256), dim3(256), 0, stream>>>(B1h, B1l);
  w2_kernel<<<dim3(896), dim3(256), 0, stream>>>(W2h, W2l);
  zero16_kernel<<<dim3(3648), dim3(256), 0, stream>>>((u32*)B2th);
  band_kernel<<<dim3(NPIX / 256), dim3(256), 0, stream>>>(band);

  gemmA_kernel<<<dim3(2, 224), dim3(256), 0, stream>>>(
      (const bf16*)Gh, (const bf16*)Gl, (const bf16*)B1h, (const bf16*)B1l, B2th, B2tl);
  gemmB_kernel<<<dim3(57, 7), dim3(256), 0, stream>>>(
      (const bf16*)W2h, (const bf16*)W2l, (const bf16*)B2th, (const bf16*)B2tl, mag);

  stats_partial_kernel<<<dim3(NCHUNK, BATCH), dim3(256), 0, stream>>>(mag, band, part);
  stats_final_kernel<<<dim3(BATCH), dim3(64), 0, stream>>>(part, stats);
  mlp_kernel<<<dim3(BATCH * 8), dim3(256), 0, stream>>>(stats, W1, b1, gamma, beta, W2m, b2, out);
}

// Round 4
// 81.087 us; speedup vs baseline: 5.8508x; 1.3333x over previous
//
#include <hip/hip_runtime.h>
#include <math.h>

#define IMG 224
#define NPIX 50176
#define BATCH 64
#define EDIM 256
#define NCHUNK 28
#define CHUNKPIX 1792

typedef _Float16 f16;
typedef __attribute__((ext_vector_type(8))) _Float16 f16x8;
typedef __attribute__((ext_vector_type(4))) _Float16 f16x4;
typedef __attribute__((ext_vector_type(4))) float f32x4;
typedef unsigned short u16;
typedef unsigned int u32;

// GEMM geometry: block 64(M) x 128(N), BK=64, 256 threads = 4 waves (2x2),
// wave tile 32x64 = 2x4 frags of 16x16, mfma_f32_16x16x32_f16.
// Split-fp16: A-operand = hi+lo planes (2 passes), B-operand = single fp16.
// Stage A: A=gray[14336][256] (224 valid k), B=B1[256][256] (226 valid rows) -> Y
// Stage B: A=W2[448][448] (rows 2u=re,2u+1=im), B=B2t[7296][448] (7232 valid) -> F

#define GLD16(gp, lp)                                                          \
  __builtin_amdgcn_global_load_lds(                                            \
      (const __attribute__((address_space(1))) u32*)(gp),                      \
      (__attribute__((address_space(3))) u32*)(lp), 16, 0, 0)

// ---- shared GEMM core (A split hi/lo, B single; 2 fused passes) ----------
template <int LDK>
__device__ __forceinline__ void gemm_core(const f16* __restrict__ Ah,
                                          const f16* __restrict__ Al,
                                          const f16* __restrict__ B,
                                          int m0, int n0,
                                          f16 (*AsH)[64], f16 (*AsL)[64],
                                          f16 (*Bs)[64], f32x4 acc[2][4]) {
  int tid = threadIdx.x;
  int lane = tid & 63, wid = tid >> 6;
  int wr = wid >> 1, wc = wid & 1;
  int srow = lane >> 3;            // row within 8-row chunk
  int sslot = lane & 7;            // physical 16B slot within 128B row
  int sk8 = sslot ^ (srow & 7);    // pre-swizzled source slot (involution)

#pragma unroll 1
  for (int k0 = 0; k0 < LDK; k0 += 64) {
    // stage 32 KB: AsH 8 chunks, AsL 8 chunks, Bs 16 chunks; 8 per wave
#pragma unroll
    for (int ci = 0; ci < 8; ++ci) {
      int c = wid * 8 + ci;
      if (c < 8) {
        GLD16(Ah + (size_t)(m0 + c * 8 + srow) * LDK + k0 + sk8 * 8,
              &AsH[0][0] + c * 512);
      } else if (c < 16) {
        int j = c - 8;
        GLD16(Al + (size_t)(m0 + j * 8 + srow) * LDK + k0 + sk8 * 8,
              &AsL[0][0] + j * 512);
      } else {
        int j = c - 16;
        GLD16(B + (size_t)(n0 + j * 8 + srow) * LDK + k0 + sk8 * 8,
              &Bs[0][0] + j * 512);
      }
    }
    __syncthreads();
#pragma unroll
    for (int kk = 0; kk < 2; ++kk) {
      f16x8 ah[2], al[2], bfr[4];
#pragma unroll
      for (int mi = 0; mi < 2; ++mi) {
        int row = wr * 32 + mi * 16 + (lane & 15);
        int slot = (kk * 4 + (lane >> 4)) ^ (row & 7);
        ah[mi] = *(const f16x8*)&AsH[row][slot * 8];
        al[mi] = *(const f16x8*)&AsL[row][slot * 8];
      }
#pragma unroll
      for (int nj = 0; nj < 4; ++nj) {
        int row = wc * 64 + nj * 16 + (lane & 15);
        int slot = (kk * 4 + (lane >> 4)) ^ (row & 7);
        bfr[nj] = *(const f16x8*)&Bs[row][slot * 8];
      }
#pragma unroll
      for (int mi = 0; mi < 2; ++mi)
#pragma unroll
        for (int nj = 0; nj < 4; ++nj)
          acc[mi][nj] = __builtin_amdgcn_mfma_f32_16x16x32_f16(
              ah[mi], bfr[nj], acc[mi][nj], 0, 0, 0);
#pragma unroll
      for (int mi = 0; mi < 2; ++mi)
#pragma unroll
        for (int nj = 0; nj < 4; ++nj)
          acc[mi][nj] = __builtin_amdgcn_mfma_f32_16x16x32_f16(
              al[mi], bfr[nj], acc[mi][nj], 0, 0, 0);
    }
    __syncthreads();
  }
}

// ---- stage A: Y = gray * B1^T; epilogue writes single-fp16 B2t ------------
__global__ __launch_bounds__(256) void gemmA_kernel(const f16* __restrict__ Gh,
                                                    const f16* __restrict__ Gl,
                                                    const f16* __restrict__ B1,
                                                    f16* __restrict__ B2t) {
  __shared__ f16 AsH[64][64];
  __shared__ f16 AsL[64][64];
  __shared__ f16 Bs[128][64];
  int m0 = blockIdx.y * 64, n0 = blockIdx.x * 128;
  f32x4 acc[2][4];
#pragma unroll
  for (int i = 0; i < 2; ++i)
#pragma unroll
    for (int j = 0; j < 4; ++j) acc[i][j] = (f32x4){0.f, 0.f, 0.f, 0.f};

  gemm_core<256>(Gh, Gl, B1, m0, n0, AsH, AsL, Bs, acc);

  int lane = threadIdx.x & 63, wid = threadIdx.x >> 6;
  int wr = wid >> 1, wc = wid & 1;
  int mbase = m0 + wr * 32, nbase = n0 + wc * 64;
#pragma unroll
  for (int mi = 0; mi < 2; ++mi) {
#pragma unroll
    for (int nj = 0; nj < 4; ++nj) {
      int c = nbase + nj * 16 + (lane & 15);
      if (c >= 226) continue;
      int m = mbase + mi * 16 + ((lane >> 4) << 2);  // 4 consecutive rows, m%4==0
      int b = m / 224;
      int h = m - b * 224;                           // h%4==0, no batch wrap
      int v = c, kb = h;
      if (c >= 113) { v = c - 113; kb = 224 + h; }
      size_t off = (size_t)(b * 113 + v) * 448 + kb;
      f32x4 y = acc[mi][nj];
      f16x4 hv;
#pragma unroll
      for (int r = 0; r < 4; ++r) hv[r] = (f16)y[r];
      *(f16x4*)&B2t[off] = hv;
    }
  }
}

// ---- stage B: F = W2 * B2t^T; fused log1p(|F|) + fftshift + mirror --------
__global__ __launch_bounds__(256) void gemmB_kernel(const f16* __restrict__ W2h,
                                                    const f16* __restrict__ W2l,
                                                    const f16* __restrict__ B2t,
                                                    float* __restrict__ mag) {
  __shared__ f16 AsH[64][64];
  __shared__ f16 AsL[64][64];
  __shared__ f16 Bs[128][64];
  int m0 = blockIdx.y * 64, n0 = blockIdx.x * 128;
  f32x4 acc[2][4];
#pragma unroll
  for (int i = 0; i < 2; ++i)
#pragma unroll
    for (int j = 0; j < 4; ++j) acc[i][j] = (f32x4){0.f, 0.f, 0.f, 0.f};

  gemm_core<448>(W2h, W2l, B2t, m0, n0, AsH, AsL, Bs, acc);

  int lane = threadIdx.x & 63, wid = threadIdx.x >> 6;
  int wr = wid >> 1, wc = wid & 1;
  int rbase = m0 + wr * 32, nbase = n0 + wc * 64;
#pragma unroll
  for (int mi = 0; mi < 2; ++mi) {
#pragma unroll
    for (int nj = 0; nj < 4; ++nj) {
      int n = nbase + nj * 16 + (lane & 15);
      if (n >= 7232) continue;
      int b = n / 113;
      int v = n - b * 113;                 // 0..112
      int rr = rbase + mi * 16 + ((lane >> 4) << 2);  // rr%4==0, rr<448
      int u0 = rr >> 1;
      f32x4 f = acc[mi][nj];
      float* magb = mag + (size_t)b * NPIX;
#pragma unroll
      for (int p = 0; p < 2; ++p) {
        float re = f[2 * p], im = f[2 * p + 1];
        int u = u0 + p;
        float mv = log1pf(sqrtf(re * re + im * im));
        int us = u + 112; if (us >= 224) us -= 224;
        int vs = v + 112; if (vs >= 224) vs -= 224;
        magb[us * IMG + vs] = mv;
        int u2 = (u == 0) ? 0 : 224 - u;
        int v2 = (v == 0) ? 0 : 224 - v;
        int us2 = u2 + 112; if (us2 >= 224) us2 -= 224;
        int vs2 = v2 + 112; if (vs2 >= 224) vs2 -= 224;
        magb[us2 * IMG + vs2] = mv;
      }
    }
  }
}

// ---- prep: gray + split fp16 ---------------------------------------------
__global__ __launch_bounds__(256) void gray_split_kernel(const float* __restrict__ x,
                                                         f16* __restrict__ Gh,
                                                         f16* __restrict__ Gl) {
  int m = blockIdx.x;        // 0..14335 = b*224 + h
  int k = threadIdx.x;       // 0..255
  float g = 0.f;
  if (k < 224) {
    int b = m / 224, h = m - b * 224;
    const float* xb = x + (size_t)b * 3 * NPIX + h * IMG + k;
    g = (xb[0] + xb[NPIX] + xb[2 * NPIX]) * (1.0f / 3.0f);
  }
  f16 hv = (f16)g;
  Gh[(size_t)m * 256 + k] = hv;
  Gl[(size_t)m * 256 + k] = (f16)(g - (float)hv);
}

// ---- fused tables: B1 | W2 hi/lo | B2t pad-row zero | band ---------------
// blocks [0,256) b1; [256,1040) w2; [1040,1096) zeropad; [1096,1292) band
__global__ __launch_bounds__(256) void tables_kernel(f16* __restrict__ B1,
                                                     f16* __restrict__ W2h,
                                                     f16* __restrict__ W2l,
                                                     f16* __restrict__ B2t,
                                                     unsigned char* __restrict__ band) {
  int blk = blockIdx.x;
  int tid = threadIdx.x;
  if (blk < 256) {
    int n = blk, k = tid;
    float val = 0.f;
    if (k < 224 && n < 226) {
      int v = (n < 113) ? n : n - 113;
      int m = (k * v) % 224;
      float mf = (float)m / 112.0f;
      val = (n < 113) ? cospif(mf) : -sinpif(mf);
    }
    B1[n * 256 + k] = (f16)val;
  } else if (blk < 1040) {
    int i = (blk - 256) * 256 + tid;       // 0..200703
    int row = i / 448;
    int k = i - row * 448;
    int u = row >> 1;
    bool imrow = row & 1;
    bool kim = k >= 224;
    int kk = kim ? k - 224 : k;
    int m = (u * kk) % 224;
    float mf = (float)m / 112.0f;
    float c = cospif(mf), s = sinpif(mf);
    // F_re = cos*Yr + sin*Yi ; F_im = -sin*Yr + cos*Yi
    float val = imrow ? (kim ? c : -s) : (kim ? s : c);
    f16 hv = (f16)val;
    W2h[i] = hv;
    W2l[i] = (f16)(val - (float)hv);
  } else if (blk < 1096) {
    int w = (blk - 1040) * 256 + tid;      // 0..14335 u32 words
    ((u32*)(B2t + (size_t)7232 * 448))[w] = 0;
  } else {
    int p = (blk - 1096) * 256 + tid;      // 0..50175
    int u = p / IMG, v = p % IMG;
    int dx = v - 112, dy = u - 112;
    float r = sqrtf((float)(dx * dx + dy * dy));
    float step = (float)(158.39191898578665 / 8.0);
    unsigned char bd = 255;
#pragma unroll
    for (int k = 0; k < 8; k++) {
      float lo = step * (float)k;
      float hi = step * (float)(k + 1);
      if (r >= lo && r < hi) bd = (unsigned char)k;
    }
    band[p] = bd;
  }
}

// ---- two-stage per-image stats -------------------------------------------
// layout: [0]=gsum [1]=gsumsq [2+k]=s1 [10+k]=s2 [18+k]=max [26+k]=count
__global__ __launch_bounds__(256) void stats_partial_kernel(
    const float* __restrict__ mag, const unsigned char* __restrict__ band,
    float* __restrict__ part) {
  int chunk = blockIdx.x;   // 0..27
  int b = blockIdx.y;       // 0..63
  int tid = threadIdx.x;
  const float* mb = mag + (size_t)b * NPIX + chunk * CHUNKPIX;
  const unsigned char* bb = band + chunk * CHUNKPIX;

  float gsum = 0.0f, gsq = 0.0f;
  float s1[8] = {0}, s2[8] = {0}, cnt[8] = {0}, mx[8];
#pragma unroll
  for (int k = 0; k < 8; k++) mx[k] = -1e30f;

#pragma unroll
  for (int i = 0; i < 7; i++) {   // 7*256 = 1792 pixels
    int p = i * 256 + tid;
    float v = mb[p];
    int bt = bb[p];
    gsum += v;
    gsq += v * v;
#pragma unroll
    for (int k = 0; k < 8; k++) {
      bool m = (bt == k);
      s1[k] += m ? v : 0.0f;
      s2[k] += m ? v * v : 0.0f;
      cnt[k] += m ? 1.0f : 0.0f;
      mx[k] = m ? fmaxf(mx[k], v) : mx[k];
    }
  }

  float vals[34];
  vals[0] = gsum; vals[1] = gsq;
#pragma unroll
  for (int k = 0; k < 8; k++) {
    vals[2 + k] = s1[k]; vals[10 + k] = s2[k]; vals[18 + k] = mx[k]; vals[26 + k] = cnt[k];
  }
#pragma unroll
  for (int i = 0; i < 34; i++) {
    float v = vals[i];
    const bool isMax = (i >= 18 && i < 26);
#pragma unroll
    for (int off = 32; off > 0; off >>= 1) {
      float o = __shfl_down(v, off);
      v = isMax ? fmaxf(v, o) : (v + o);
    }
    vals[i] = v;
  }
  __shared__ float red[4][34];
  int w = tid >> 6;
  if ((tid & 63) == 0) {
#pragma unroll
    for (int i = 0; i < 34; i++) red[w][i] = vals[i];
  }
  __syncthreads();
  if (tid < 34) {
    bool isMax = (tid >= 18 && tid < 26);
    float v = red[0][tid];
    for (int ww = 1; ww < 4; ww++) v = isMax ? fmaxf(v, red[ww][tid]) : (v + red[ww][tid]);
    part[((size_t)b * NCHUNK + chunk) * 34 + tid] = v;
  }
}

__global__ __launch_bounds__(64) void stats_final_kernel(const float* __restrict__ part,
                                                         float* __restrict__ stats) {
  int b = blockIdx.x;
  int t = threadIdx.x;
  if (t >= 34) return;
  bool isMax = (t >= 18 && t < 26);
  const float* pb = part + (size_t)b * NCHUNK * 34;
  float v = pb[t];
#pragma unroll
  for (int c = 1; c < NCHUNK; c++) {
    float o = pb[c * 34 + t];
    v = isMax ? fmaxf(v, o) : (v + o);
  }
  stats[b * 34 + t] = v;
}

// ---- MLP ------------------------------------------------------------------
__global__ __launch_bounds__(256) void mlp_kernel(const float* __restrict__ stats,
                                                  const float* __restrict__ W1,
                                                  const float* __restrict__ b1,
                                                  const float* __restrict__ gamma,
                                                  const float* __restrict__ beta,
                                                  const float* __restrict__ W2m,
                                                  const float* __restrict__ b2,
                                                  float* __restrict__ out) {
  int bk = blockIdx.x;
  int b = bk >> 3, k = bk & 7;
  int e = threadIdx.x;
  const float* st = stats + b * 34;
  const float N = (float)NPIX;

  float mu = st[0] / N;
  float varg = fmaxf(st[1] - N * mu * mu, 0.0f) / (N - 1.0f);
  float sd = sqrtf(varg) + 1e-6f;

  float s1r = st[2 + k], s2r = st[10 + k], mxr = st[18 + k], cntk = st[26 + k];
  float ms = cntk + 1e-6f;
  float s1n = (s1r - mu * cntk) / sd;
  float s2n = (s2r - 2.0f * mu * s1r + mu * mu * cntk) / (sd * sd);
  float mean_k = s1n / ms;
  float var_num = s2n - 2.0f * mean_k * s1n + mean_k * mean_k * cntk;
  float std_k = sqrtf(var_num / ms + 1e-6f);
  float max_k = (mxr - mu) / sd;

  float h = mean_k * W1[e] + std_k * W1[EDIM + e] + max_k * W1[2 * EDIM + e] + b1[e];

  float s = h, q = h * h;
#pragma unroll
  for (int off = 32; off > 0; off >>= 1) {
    s += __shfl_down(s, off);
    q += __shfl_down(q, off);
  }
  __shared__ float rs[4], rq[4];
  __shared__ float hmS, hvS;
  if ((e & 63) == 0) { rs[e >> 6] = s; rq[e >> 6] = q; }
  __syncthreads();
  if (e == 0) {
    float ts = rs[0] + rs[1] + rs[2] + rs[3];
    float tq = rq[0] + rq[1] + rq[2] + rq[3];
    float hm = ts / 256.0f;
    hmS = hm;
    hvS = fmaxf(tq / 256.0f - hm * hm, 0.0f);
  }
  __syncthreads();
  float hn = (h - hmS) / sqrtf(hvS + 1e-5f) * gamma[e] + beta[e];
  float hr = fmaxf(hn, 0.0f);

  __shared__ float hs[EDIM];
  hs[e] = hr;
  __syncthreads();

  float acc = b2[e];
#pragma unroll 8
  for (int j = 0; j < EDIM; j++) acc += hs[j] * W2m[j * EDIM + e];
  out[(size_t)bk * EDIM + e] = acc;
}

// ---- launch ---------------------------------------------------------------
extern "C" void kernel_launch(void* const* d_in, const int* in_sizes, int n_in,
                              void* d_out, int out_size, void* d_ws, size_t ws_size,
                              hipStream_t stream) {
  const float* x     = (const float*)d_in[0];
  const float* W1    = (const float*)d_in[1];
  const float* b1    = (const float*)d_in[2];
  const float* gamma = (const float*)d_in[3];
  const float* beta  = (const float*)d_in[4];
  const float* W2m   = (const float*)d_in[5];
  const float* b2    = (const float*)d_in[6];
  float* out = (float*)d_out;

  char* W = (char*)d_ws;
  // R1: Gh, Gl (7,340,032 B each) -- later aliased by mag (12,845,056 B)
  f16* Gh = (f16*)W;
  f16* Gl = Gh + (size_t)14336 * 256;
  float* mag = (float*)W;
  // R2: B2t single plane [7296][448] = 6,537,216 B
  f16* B2t = (f16*)(W + 14680064);
  // R3: small tables
  char* R3 = W + 14680064 + 6537216;
  f16* B1  = (f16*)R3;                             // 131,072 B
  f16* W2h = (f16*)(R3 + 131072);                  // 401,408 B
  f16* W2l = (f16*)(R3 + 131072 + 401408);         // 401,408 B
  unsigned char* band = (unsigned char*)(R3 + 131072 + 2 * 401408);  // 50,176 B
  float* stats = (float*)(R3 + 131072 + 2 * 401408 + 50176);
  float* part = stats + BATCH * 34;                // 64*28*34 floats

  gray_split_kernel<<<dim3(14336), dim3(256), 0, stream>>>(x, Gh, Gl);
  tables_kernel<<<dim3(1292), dim3(256), 0, stream>>>(B1, W2h, W2l, B2t, band);

  gemmA_kernel<<<dim3(2, 224), dim3(256), 0, stream>>>(Gh, Gl, B1, B2t);
  gemmB_kernel<<<dim3(57, 7), dim3(256), 0, stream>>>(W2h, W2l, B2t, mag);

  stats_partial_kernel<<<dim3(NCHUNK, BATCH), dim3(256), 0, stream>>>(mag, band, part);
  stats_final_kernel<<<dim3(BATCH), dim3(64), 0, stream>>>(part, stats);
  mlp_kernel<<<dim3(BATCH * 8), dim3(256), 0, stream>>>(stats, W1, b1, gamma, beta, W2m, b2, out);
}

// Round 5
// 72.927 us; speedup vs baseline: 6.5054x; 1.1119x over previous
//
#include <hip/hip_runtime.h>
#include <math.h>

#define IMG 224
#define NPIX 50176
#define BATCH 64
#define EDIM 256
#define NCHUNK 28
#define CHUNKPIX 1792

typedef _Float16 f16;
typedef __attribute__((ext_vector_type(8))) _Float16 f16x8;
typedef __attribute__((ext_vector_type(4))) _Float16 f16x4;
typedef __attribute__((ext_vector_type(4))) float f32x4;
typedef unsigned int u32;

// GEMM geometry: block 64(M) x 128(N), BK=64, 256 threads = 4 waves (2x2),
// wave tile 32x64 = 2x4 frags of 16x16, mfma_f32_16x16x32_f16, single fp16.
// A layout [M][LDK] k-contiguous; B layout [N][LDK] k-contiguous (TN gemm).
// Stage A: A=gray[14336][256] (224 valid k), B=B1[256][256] (226 valid rows) -> Y
// Stage B: A=W2[448][448] (rows 2u=re,2u+1=im), B=B2t[7296][448] (7232 valid) -> F

#define GLD16(gp, lp)                                                          \
  __builtin_amdgcn_global_load_lds(                                            \
      (const __attribute__((address_space(1))) u32*)(gp),                      \
      (__attribute__((address_space(3))) u32*)(lp), 16, 0, 0)

// ---- shared GEMM core (single fp16) --------------------------------------
template <int LDK>
__device__ __forceinline__ void gemm_core(const f16* __restrict__ A,
                                          const f16* __restrict__ B,
                                          int m0, int n0,
                                          f16 (*As)[64], f16 (*Bs)[64],
                                          f32x4 acc[2][4]) {
  int tid = threadIdx.x;
  int lane = tid & 63, wid = tid >> 6;
  int wr = wid >> 1, wc = wid & 1;
  int srow = lane >> 3;            // row within 8-row chunk
  int sslot = lane & 7;            // physical 16B slot within 128B row
  int sk8 = sslot ^ (srow & 7);    // pre-swizzled source slot (involution)

#pragma unroll 1
  for (int k0 = 0; k0 < LDK; k0 += 64) {
    // stage 24 KB: As 8 chunks (64 rows), Bs 16 chunks (128 rows); 6 per wave
#pragma unroll
    for (int ci = 0; ci < 6; ++ci) {
      int c = wid * 6 + ci;
      if (c < 8) {
        GLD16(A + (size_t)(m0 + c * 8 + srow) * LDK + k0 + sk8 * 8,
              &As[0][0] + c * 512);
      } else {
        int j = c - 8;
        GLD16(B + (size_t)(n0 + j * 8 + srow) * LDK + k0 + sk8 * 8,
              &Bs[0][0] + j * 512);
      }
    }
    __syncthreads();
#pragma unroll
    for (int kk = 0; kk < 2; ++kk) {
      f16x8 af[2], bfr[4];
#pragma unroll
      for (int mi = 0; mi < 2; ++mi) {
        int row = wr * 32 + mi * 16 + (lane & 15);
        int slot = (kk * 4 + (lane >> 4)) ^ (row & 7);
        af[mi] = *(const f16x8*)&As[row][slot * 8];
      }
#pragma unroll
      for (int nj = 0; nj < 4; ++nj) {
        int row = wc * 64 + nj * 16 + (lane & 15);
        int slot = (kk * 4 + (lane >> 4)) ^ (row & 7);
        bfr[nj] = *(const f16x8*)&Bs[row][slot * 8];
      }
#pragma unroll
      for (int mi = 0; mi < 2; ++mi)
#pragma unroll
        for (int nj = 0; nj < 4; ++nj)
          acc[mi][nj] = __builtin_amdgcn_mfma_f32_16x16x32_f16(
              af[mi], bfr[nj], acc[mi][nj], 0, 0, 0);
    }
    __syncthreads();
  }
}

// ---- stage A: Y = gray * B1^T; epilogue writes fp16 B2t -------------------
__global__ __launch_bounds__(256) void gemmA_kernel(const f16* __restrict__ Gh,
                                                    const f16* __restrict__ B1,
                                                    f16* __restrict__ B2t) {
  __shared__ f16 As[64][64];
  __shared__ f16 Bs[128][64];
  int m0 = blockIdx.y * 64, n0 = blockIdx.x * 128;
  f32x4 acc[2][4];
#pragma unroll
  for (int i = 0; i < 2; ++i)
#pragma unroll
    for (int j = 0; j < 4; ++j) acc[i][j] = (f32x4){0.f, 0.f, 0.f, 0.f};

  gemm_core<256>(Gh, B1, m0, n0, As, Bs, acc);

  int lane = threadIdx.x & 63, wid = threadIdx.x >> 6;
  int wr = wid >> 1, wc = wid & 1;
  int mbase = m0 + wr * 32, nbase = n0 + wc * 64;
#pragma unroll
  for (int mi = 0; mi < 2; ++mi) {
#pragma unroll
    for (int nj = 0; nj < 4; ++nj) {
      int c = nbase + nj * 16 + (lane & 15);
      if (c >= 226) continue;
      int m = mbase + mi * 16 + ((lane >> 4) << 2);  // 4 consecutive rows, m%4==0
      int b = m / 224;
      int h = m - b * 224;                           // h%4==0, no batch wrap
      int v = c, kb = h;
      if (c >= 113) { v = c - 113; kb = 224 + h; }
      size_t off = (size_t)(b * 113 + v) * 448 + kb;
      f32x4 y = acc[mi][nj];
      f16x4 hv;
#pragma unroll
      for (int r = 0; r < 4; ++r) hv[r] = (f16)y[r];
      *(f16x4*)&B2t[off] = hv;
    }
  }
}

// ---- stage B: F = W2 * B2t^T; fused log1p(|F|) + fftshift + mirror --------
__global__ __launch_bounds__(256) void gemmB_kernel(const f16* __restrict__ W2h,
                                                    const f16* __restrict__ B2t,
                                                    float* __restrict__ mag) {
  __shared__ f16 As[64][64];
  __shared__ f16 Bs[128][64];
  int m0 = blockIdx.y * 64, n0 = blockIdx.x * 128;
  f32x4 acc[2][4];
#pragma unroll
  for (int i = 0; i < 2; ++i)
#pragma unroll
    for (int j = 0; j < 4; ++j) acc[i][j] = (f32x4){0.f, 0.f, 0.f, 0.f};

  gemm_core<448>(W2h, B2t, m0, n0, As, Bs, acc);

  int lane = threadIdx.x & 63, wid = threadIdx.x >> 6;
  int wr = wid >> 1, wc = wid & 1;
  int rbase = m0 + wr * 32, nbase = n0 + wc * 64;
#pragma unroll
  for (int mi = 0; mi < 2; ++mi) {
#pragma unroll
    for (int nj = 0; nj < 4; ++nj) {
      int n = nbase + nj * 16 + (lane & 15);
      if (n >= 7232) continue;
      int b = n / 113;
      int v = n - b * 113;                 // 0..112
      int rr = rbase + mi * 16 + ((lane >> 4) << 2);  // rr%4==0, rr<448
      int u0 = rr >> 1;
      f32x4 f = acc[mi][nj];
      float* magb = mag + (size_t)b * NPIX;
#pragma unroll
      for (int p = 0; p < 2; ++p) {
        float re = f[2 * p], im = f[2 * p + 1];
        int u = u0 + p;
        float mv = log1pf(sqrtf(re * re + im * im));
        int us = u + 112; if (us >= 224) us -= 224;
        int vs = v + 112; if (vs >= 224) vs -= 224;
        magb[us * IMG + vs] = mv;
        int u2 = (u == 0) ? 0 : 224 - u;
        int v2 = (v == 0) ? 0 : 224 - v;
        int us2 = u2 + 112; if (us2 >= 224) us2 -= 224;
        int vs2 = v2 + 112; if (vs2 >= 224) vs2 -= 224;
        magb[us2 * IMG + vs2] = mv;
      }
    }
  }
}

// ---- fused prep: gray | B1 | W2 | B2t pad zero | band --------------------
// blocks [0,14336) gray; [14336,14592) b1; [14592,15376) w2;
//        [15376,15432) zeropad; [15432,15628) band
__global__ __launch_bounds__(256) void prep_kernel(const float* __restrict__ x,
                                                   f16* __restrict__ Gh,
                                                   f16* __restrict__ B1,
                                                   f16* __restrict__ W2h,
                                                   f16* __restrict__ B2t,
                                                   unsigned char* __restrict__ band) {
  int blk = blockIdx.x;
  int tid = threadIdx.x;
  if (blk < 14336) {
    int m = blk, k = tid;
    float g = 0.f;
    if (k < 224) {
      int b = m / 224, h = m - b * 224;
      const float* xb = x + (size_t)b * 3 * NPIX + h * IMG + k;
      g = (xb[0] + xb[NPIX] + xb[2 * NPIX]) * (1.0f / 3.0f);
    }
    Gh[(size_t)m * 256 + k] = (f16)g;
  } else if (blk < 14592) {
    int n = blk - 14336, k = tid;
    float val = 0.f;
    if (k < 224 && n < 226) {
      int v = (n < 113) ? n : n - 113;
      int m = (k * v) % 224;
      float mf = (float)m / 112.0f;
      val = (n < 113) ? cospif(mf) : -sinpif(mf);
    }
    B1[n * 256 + k] = (f16)val;
  } else if (blk < 15376) {
    int i = (blk - 14592) * 256 + tid;     // 0..200703
    int row = i / 448;
    int k = i - row * 448;
    int u = row >> 1;
    bool imrow = row & 1;
    bool kim = k >= 224;
    int kk = kim ? k - 224 : k;
    int m = (u * kk) % 224;
    float mf = (float)m / 112.0f;
    float c = cospif(mf), s = sinpif(mf);
    // F_re = cos*Yr + sin*Yi ; F_im = -sin*Yr + cos*Yi
    float val = imrow ? (kim ? c : -s) : (kim ? s : c);
    W2h[i] = (f16)val;
  } else if (blk < 15432) {
    int w = (blk - 15376) * 256 + tid;     // 0..14335 u32 words (64 pad rows)
    ((u32*)(B2t + (size_t)7232 * 448))[w] = 0;
  } else {
    int p = (blk - 15432) * 256 + tid;     // 0..50175
    int u = p / IMG, v = p % IMG;
    int dx = v - 112, dy = u - 112;
    float r = sqrtf((float)(dx * dx + dy * dy));
    float step = (float)(158.39191898578665 / 8.0);
    unsigned char bd = 255;
#pragma unroll
    for (int k = 0; k < 8; k++) {
      float lo = step * (float)k;
      float hi = step * (float)(k + 1);
      if (r >= lo && r < hi) bd = (unsigned char)k;
    }
    band[p] = bd;
  }
}

// ---- per-image stats, stage 1 --------------------------------------------
// layout: [0]=gsum [1]=gsumsq [2+k]=s1 [10+k]=s2 [18+k]=max [26+k]=count
__global__ __launch_bounds__(256) void stats_partial_kernel(
    const float* __restrict__ mag, const unsigned char* __restrict__ band,
    float* __restrict__ part) {
  int chunk = blockIdx.x;   // 0..27
  int b = blockIdx.y;       // 0..63
  int tid = threadIdx.x;
  const float* mb = mag + (size_t)b * NPIX + chunk * CHUNKPIX;
  const unsigned char* bb = band + chunk * CHUNKPIX;

  float gsum = 0.0f, gsq = 0.0f;
  float s1[8] = {0}, s2[8] = {0}, cnt[8] = {0}, mx[8];
#pragma unroll
  for (int k = 0; k < 8; k++) mx[k] = -1e30f;

#pragma unroll
  for (int i = 0; i < 7; i++) {   // 7*256 = 1792 pixels
    int p = i * 256 + tid;
    float v = mb[p];
    int bt = bb[p];
    gsum += v;
    gsq += v * v;
#pragma unroll
    for (int k = 0; k < 8; k++) {
      bool m = (bt == k);
      s1[k] += m ? v : 0.0f;
      s2[k] += m ? v * v : 0.0f;
      cnt[k] += m ? 1.0f : 0.0f;
      mx[k] = m ? fmaxf(mx[k], v) : mx[k];
    }
  }

  float vals[34];
  vals[0] = gsum; vals[1] = gsq;
#pragma unroll
  for (int k = 0; k < 8; k++) {
    vals[2 + k] = s1[k]; vals[10 + k] = s2[k]; vals[18 + k] = mx[k]; vals[26 + k] = cnt[k];
  }
#pragma unroll
  for (int i = 0; i < 34; i++) {
    float v = vals[i];
    const bool isMax = (i >= 18 && i < 26);
#pragma unroll
    for (int off = 32; off > 0; off >>= 1) {
      float o = __shfl_down(v, off);
      v = isMax ? fmaxf(v, o) : (v + o);
    }
    vals[i] = v;
  }
  __shared__ float red[4][34];
  int w = tid >> 6;
  if ((tid & 63) == 0) {
#pragma unroll
    for (int i = 0; i < 34; i++) red[w][i] = vals[i];
  }
  __syncthreads();
  if (tid < 34) {
    bool isMax = (tid >= 18 && tid < 26);
    float v = red[0][tid];
    for (int ww = 1; ww < 4; ww++) v = isMax ? fmaxf(v, red[ww][tid]) : (v + red[ww][tid]);
    part[((size_t)b * NCHUNK + chunk) * 34 + tid] = v;
  }
}

// ---- MLP (with fused stage-2 stats reduction) -----------------------------
__global__ __launch_bounds__(256) void mlp_kernel(const float* __restrict__ part,
                                                  const float* __restrict__ W1,
                                                  const float* __restrict__ b1,
                                                  const float* __restrict__ gamma,
                                                  const float* __restrict__ beta,
                                                  const float* __restrict__ W2m,
                                                  const float* __restrict__ b2,
                                                  float* __restrict__ out) {
  int bk = blockIdx.x;
  int b = bk >> 3, k = bk & 7;
  int e = threadIdx.x;

  __shared__ float st[34];
  if (e < 34) {
    bool isMax = (e >= 18 && e < 26);
    const float* pb = part + (size_t)b * NCHUNK * 34;
    float v = pb[e];
#pragma unroll
    for (int c = 1; c < NCHUNK; c++) {
      float o = pb[c * 34 + e];
      v = isMax ? fmaxf(v, o) : (v + o);
    }
    st[e] = v;
  }
  __syncthreads();

  const float N = (float)NPIX;
  float mu = st[0] / N;
  float varg = fmaxf(st[1] - N * mu * mu, 0.0f) / (N - 1.0f);
  float sd = sqrtf(varg) + 1e-6f;

  float s1r = st[2 + k], s2r = st[10 + k], mxr = st[18 + k], cntk = st[26 + k];
  float ms = cntk + 1e-6f;
  float s1n = (s1r - mu * cntk) / sd;
  float s2n = (s2r - 2.0f * mu * s1r + mu * mu * cntk) / (sd * sd);
  float mean_k = s1n / ms;
  float var_num = s2n - 2.0f * mean_k * s1n + mean_k * mean_k * cntk;
  float std_k = sqrtf(var_num / ms + 1e-6f);
  float max_k = (mxr - mu) / sd;

  float h = mean_k * W1[e] + std_k * W1[EDIM + e] + max_k * W1[2 * EDIM + e] + b1[e];

  float s = h, q = h * h;
#pragma unroll
  for (int off = 32; off > 0; off >>= 1) {
    s += __shfl_down(s, off);
    q += __shfl_down(q, off);
  }
  __shared__ float rs[4], rq[4];
  __shared__ float hmS, hvS;
  if ((e & 63) == 0) { rs[e >> 6] = s; rq[e >> 6] = q; }
  __syncthreads();
  if (e == 0) {
    float ts = rs[0] + rs[1] + rs[2] + rs[3];
    float tq = rq[0] + rq[1] + rq[2] + rq[3];
    float hm = ts / 256.0f;
    hmS = hm;
    hvS = fmaxf(tq / 256.0f - hm * hm, 0.0f);
  }
  __syncthreads();
  float hn = (h - hmS) / sqrtf(hvS + 1e-5f) * gamma[e] + beta[e];
  float hr = fmaxf(hn, 0.0f);

  __shared__ float hs[EDIM];
  hs[e] = hr;
  __syncthreads();

  float acc = b2[e];
#pragma unroll 8
  for (int j = 0; j < EDIM; j++) acc += hs[j] * W2m[j * EDIM + e];
  out[(size_t)bk * EDIM + e] = acc;
}

// ---- launch ---------------------------------------------------------------
extern "C" void kernel_launch(void* const* d_in, const int* in_sizes, int n_in,
                              void* d_out, int out_size, void* d_ws, size_t ws_size,
                              hipStream_t stream) {
  const float* x     = (const float*)d_in[0];
  const float* W1    = (const float*)d_in[1];
  const float* b1    = (const float*)d_in[2];
  const float* gamma = (const float*)d_in[3];
  const float* beta  = (const float*)d_in[4];
  const float* W2m   = (const float*)d_in[5];
  const float* b2    = (const float*)d_in[6];
  float* out = (float*)d_out;

  char* W = (char*)d_ws;
  // R1: Gh [14336][256] f16 = 7,340,032 B -- later aliased by mag (12,845,056 B)
  f16* Gh = (f16*)W;
  float* mag = (float*)W;
  // R2: B2t [7296][448] f16 = 6,537,216 B
  f16* B2t = (f16*)(W + 14680064);
  // R3: small tables
  char* R3 = W + 14680064 + 6537216;
  f16* B1  = (f16*)R3;                             // 131,072 B
  f16* W2h = (f16*)(R3 + 131072);                  // 401,408 B
  unsigned char* band = (unsigned char*)(R3 + 131072 + 401408);  // 50,176 B
  float* part = (float*)(R3 + 131072 + 401408 + 50176);          // 64*28*34*4 B

  prep_kernel<<<dim3(15628), dim3(256), 0, stream>>>(x, Gh, B1, W2h, B2t, band);
  gemmA_kernel<<<dim3(2, 224), dim3(256), 0, stream>>>(Gh, B1, B2t);
  gemmB_kernel<<<dim3(57, 7), dim3(256), 0, stream>>>(W2h, B2t, mag);
  stats_partial_kernel<<<dim3(NCHUNK, BATCH), dim3(256), 0, stream>>>(mag, band, part);
  mlp_kernel<<<dim3(BATCH * 8), dim3(256), 0, stream>>>(part, W1, b1, gamma, beta, W2m, b2, out);
}

// Round 6
// 54.528 us; speedup vs baseline: 8.7006x; 1.3374x over previous
//
#include <hip/hip_runtime.h>
#include <math.h>

#define IMG 224
#define NPIX 50176
#define BATCH 64
#define EDIM 256

typedef _Float16 f16;
typedef __attribute__((ext_vector_type(8))) _Float16 f16x8;
typedef __attribute__((ext_vector_type(4))) _Float16 f16x4;
typedef __attribute__((ext_vector_type(4))) float f32x4;
typedef unsigned int u32;

// GEMM geometry: block 64(M) x 128(N), BK=64, 256 threads = 4 waves (2x2),
// wave tile 32x64 = 2x4 frags of 16x16, mfma_f32_16x16x32_f16, single fp16.
// Double-buffered LDS (48 KB), raw s_barrier + counted vmcnt(6) so the
// prefetch stays in flight across the barrier (T3 minimum 2-phase recipe).
// Stage A: A=gray[14336][256] (224 valid k), B=B1[256][256] -> Y (fp16 B2t)
// Stage B (per image): A=W2[448][448] (rows 2u=re,2u+1=im), B=B2t[b][128][448]
//   epilogue: log1p(|F|) + radial-band stats fused (no mag buffer).

#define GLD16(gp, lp)                                                          \
  __builtin_amdgcn_global_load_lds(                                            \
      (const __attribute__((address_space(1))) u32*)(gp),                      \
      (__attribute__((address_space(3))) u32*)(lp), 16, 0, 0)

// ---- shared GEMM core (single fp16, double-buffered, counted vmcnt) ------
template <int LDK, int NT>
__device__ __forceinline__ void gemm_core(const f16* __restrict__ A,
                                          const f16* __restrict__ B,
                                          int m0, int n0,
                                          f16 (*As)[64][64], f16 (*Bs)[128][64],
                                          f32x4 acc[2][4]) {
  int tid = threadIdx.x;
  int lane = tid & 63, wid = tid >> 6;
  int wr = wid >> 1, wc = wid & 1;
  int srow = lane >> 3;            // row within 8-row chunk
  int sk8 = (lane & 7) ^ srow;     // pre-swizzled source slot (involution)

  auto stage = [&](int bufi, int t) {
    int k0 = t * 64;
#pragma unroll
    for (int ci = 0; ci < 6; ++ci) {
      int c = wid * 6 + ci;
      if (c < 8) {
        GLD16(A + (size_t)(m0 + c * 8 + srow) * LDK + k0 + sk8 * 8,
              &As[bufi][0][0] + c * 512);
      } else {
        int j = c - 8;
        GLD16(B + (size_t)(n0 + j * 8 + srow) * LDK + k0 + sk8 * 8,
              &Bs[bufi][0][0] + j * 512);
      }
    }
  };

  stage(0, 0);
#pragma unroll 1
  for (int t = 0; t < NT; ++t) {
    int cur = t & 1;
    if (t + 1 < NT) {
      stage(cur ^ 1, t + 1);
      asm volatile("s_waitcnt vmcnt(6)" ::: "memory");   // tile t done, t+1 in flight
    } else {
      asm volatile("s_waitcnt vmcnt(0)" ::: "memory");
    }
    __builtin_amdgcn_s_barrier();
#pragma unroll
    for (int kk = 0; kk < 2; ++kk) {
      f16x8 af[2], bfr[4];
#pragma unroll
      for (int mi = 0; mi < 2; ++mi) {
        int row = wr * 32 + mi * 16 + (lane & 15);
        int slot = (kk * 4 + (lane >> 4)) ^ (row & 7);
        af[mi] = *(const f16x8*)&As[cur][row][slot * 8];
      }
#pragma unroll
      for (int nj = 0; nj < 4; ++nj) {
        int row = wc * 64 + nj * 16 + (lane & 15);
        int slot = (kk * 4 + (lane >> 4)) ^ (row & 7);
        bfr[nj] = *(const f16x8*)&Bs[cur][row][slot * 8];
      }
#pragma unroll
      for (int mi = 0; mi < 2; ++mi)
#pragma unroll
        for (int nj = 0; nj < 4; ++nj)
          acc[mi][nj] = __builtin_amdgcn_mfma_f32_16x16x32_f16(
              af[mi], bfr[nj], acc[mi][nj], 0, 0, 0);
    }
    __builtin_amdgcn_s_barrier();
  }
}

// ---- stage A: Y = gray * B1^T; epilogue writes fp16 B2t -------------------
__global__ __launch_bounds__(256) void gemmA_kernel(const f16* __restrict__ Gh,
                                                    const f16* __restrict__ B1,
                                                    f16* __restrict__ B2t) {
  __shared__ f16 As[2][64][64];
  __shared__ f16 Bs[2][128][64];
  int m0 = blockIdx.y * 64, n0 = blockIdx.x * 128;
  f32x4 acc[2][4];
#pragma unroll
  for (int i = 0; i < 2; ++i)
#pragma unroll
    for (int j = 0; j < 4; ++j) acc[i][j] = (f32x4){0.f, 0.f, 0.f, 0.f};

  gemm_core<256, 4>(Gh, B1, m0, n0, As, Bs, acc);

  int lane = threadIdx.x & 63, wid = threadIdx.x >> 6;
  int wr = wid >> 1, wc = wid & 1;
  int mbase = m0 + wr * 32, nbase = n0 + wc * 64;
#pragma unroll
  for (int mi = 0; mi < 2; ++mi) {
#pragma unroll
    for (int nj = 0; nj < 4; ++nj) {
      int c = nbase + nj * 16 + (lane & 15);
      if (c >= 226) continue;
      int m = mbase + mi * 16 + ((lane >> 4) << 2);  // 4 consecutive rows, m%4==0
      int b = m / 224;
      int h = m - b * 224;                           // h%4==0, no batch wrap
      int v = c, kb = h;
      if (c >= 113) { v = c - 113; kb = 224 + h; }
      size_t off = (size_t)(b * 128 + v) * 448 + kb;
      f32x4 y = acc[mi][nj];
      f16x4 hv;
#pragma unroll
      for (int r = 0; r < 4; ++r) hv[r] = (f16)y[r];
      *(f16x4*)&B2t[off] = hv;
    }
  }
}

// ---- stage B: F = W2 * B2t[b]^T; fused log1p(|F|) + band stats ------------
// stats layout: [0]=gsum [1]=gsumsq [2+k]=s1 [10+k]=s2 [18+k]=max [26+k]=cnt
__global__ __launch_bounds__(256) void gemmB_kernel(const f16* __restrict__ W2h,
                                                    const f16* __restrict__ B2t,
                                                    float* __restrict__ stats) {
  __shared__ f16 As[2][64][64];
  __shared__ f16 Bs[2][128][64];
  int b = blockIdx.x;                 // image
  int m0 = blockIdx.y * 64;           // W2 row block
  f32x4 acc[2][4];
#pragma unroll
  for (int i = 0; i < 2; ++i)
#pragma unroll
    for (int j = 0; j < 4; ++j) acc[i][j] = (f32x4){0.f, 0.f, 0.f, 0.f};

  gemm_core<448, 7>(W2h, B2t + (size_t)b * 128 * 448, m0, 0, As, Bs, acc);

  int tid = threadIdx.x;
  int lane = tid & 63, wid = tid >> 6;
  int wr = wid >> 1, wc = wid & 1;
  int rbase = m0 + wr * 32;
  const float step = (float)(158.39191898578665 / 8.0);

  float gsum = 0.f, gsq = 0.f;
  float s1[8] = {0}, s2[8] = {0}, cnt[8] = {0};
  float mx[8] = {0, 0, 0, 0, 0, 0, 0, 0};   // mag >= 0 always

#pragma unroll
  for (int mi = 0; mi < 2; ++mi) {
#pragma unroll
    for (int nj = 0; nj < 4; ++nj) {
      int n = wc * 64 + nj * 16 + (lane & 15);   // v, 0..127
      if (n >= 113) continue;
      // mirror pixel (224-u,224-v) has identical radius -> same band, same
      // value; it is a distinct pixel iff v in [1,111] -> weight 2.
      float wgt = (n >= 1 && n <= 111) ? 2.f : 1.f;
      float dx2 = (float)(n * n);                // |dx| = v (v=112 -> 112)
      int rr = rbase + mi * 16 + ((lane >> 4) << 2);
      f32x4 f = acc[mi][nj];
#pragma unroll
      for (int p = 0; p < 2; ++p) {
        int u = (rr >> 1) + p;
        float re = f[2 * p], im = f[2 * p + 1];
        float mv = log1pf(sqrtf(re * re + im * im));
        int a = (u <= 111) ? u : 224 - u;        // |dy| in shifted coords
        float r = sqrtf((float)(a * a) + dx2);
        int bd = 255;
#pragma unroll
        for (int k = 0; k < 8; k++) {
          float lo = step * (float)k;
          float hi = step * (float)(k + 1);
          if (r >= lo && r < hi) bd = k;
        }
        float wm = wgt * mv;
        gsum += wm;
        gsq += wm * mv;
#pragma unroll
        for (int k = 0; k < 8; k++) {
          bool m = (bd == k);
          s1[k] += m ? wm : 0.f;
          s2[k] += m ? wm * mv : 0.f;
          cnt[k] += m ? wgt : 0.f;
          mx[k] = m ? fmaxf(mx[k], mv) : mx[k];
        }
      }
    }
  }

  float vals[34];
  vals[0] = gsum; vals[1] = gsq;
#pragma unroll
  for (int k = 0; k < 8; k++) {
    vals[2 + k] = s1[k]; vals[10 + k] = s2[k]; vals[18 + k] = mx[k]; vals[26 + k] = cnt[k];
  }
#pragma unroll
  for (int i = 0; i < 34; i++) {
    float v = vals[i];
    const bool isMax = (i >= 18 && i < 26);
#pragma unroll
    for (int off = 32; off > 0; off >>= 1) {
      float o = __shfl_down(v, off);
      v = isMax ? fmaxf(v, o) : (v + o);
    }
    vals[i] = v;
  }
  float* red = (float*)&As[0][0][0];   // reuse LDS (all reads done)
  if ((tid & 63) == 0) {
#pragma unroll
    for (int i = 0; i < 34; i++) red[wid * 34 + i] = vals[i];
  }
  __syncthreads();
  if (tid < 34) {
    bool isMax = (tid >= 18 && tid < 26);
    float v = red[tid];
#pragma unroll
    for (int ww = 1; ww < 4; ww++) {
      float o = red[ww * 34 + tid];
      v = isMax ? fmaxf(v, o) : (v + o);
    }
    if (isMax)
      atomicMax((u32*)&stats[b * 34 + tid], __float_as_uint(v));  // v >= 0
    else
      atomicAdd(&stats[b * 34 + tid], v);
  }
}

// ---- fused prep: gray | B1 | W2 | B2t pad zero | stats zero --------------
// blocks [0,14336) gray; [14336,14592) b1; [14592,15376) w2;
//        [15376,16216) B2t pad rows; [16216,16225) stats zero
__global__ __launch_bounds__(256) void prep_kernel(const float* __restrict__ x,
                                                   f16* __restrict__ Gh,
                                                   f16* __restrict__ B1,
                                                   f16* __restrict__ W2h,
                                                   f16* __restrict__ B2t,
                                                   float* __restrict__ stats) {
  int blk = blockIdx.x;
  int tid = threadIdx.x;
  if (blk < 14336) {
    int m = blk, k = tid;
    float g = 0.f;
    if (k < 224) {
      int b = m / 224, h = m - b * 224;
      const float* xb = x + (size_t)b * 3 * NPIX + h * IMG + k;
      g = (xb[0] + xb[NPIX] + xb[2 * NPIX]) * (1.0f / 3.0f);
    }
    Gh[(size_t)m * 256 + k] = (f16)g;
  } else if (blk < 14592) {
    int n = blk - 14336, k = tid;
    float val = 0.f;
    if (k < 224 && n < 226) {
      int v = (n < 113) ? n : n - 113;
      int m = (k * v) % 224;
      float mf = (float)m / 112.0f;
      val = (n < 113) ? cospif(mf) : -sinpif(mf);
    }
    B1[n * 256 + k] = (f16)val;
  } else if (blk < 15376) {
    int i = (blk - 14592) * 256 + tid;     // 0..200703
    int row = i / 448;
    int k = i - row * 448;
    int u = row >> 1;
    bool imrow = row & 1;
    bool kim = k >= 224;
    int kk = kim ? k - 224 : k;
    int m = (u * kk) % 224;
    float mf = (float)m / 112.0f;
    float c = cospif(mf), s = sinpif(mf);
    // F_re = cos*Yr + sin*Yi ; F_im = -sin*Yr + cos*Yi
    float val = imrow ? (kim ? c : -s) : (kim ? s : c);
    W2h[i] = (f16)val;
  } else if (blk < 16216) {
    int w = (blk - 15376) * 256 + tid;     // 0..215039 u32 words
    int img = w / 3360;                    // 15 rows * 448 f16 / 2 per image
    int off = w - img * 3360;
    ((u32*)B2t)[(size_t)(img * 128 + 113) * 224 + off] = 0;
  } else {
    int i = (blk - 16216) * 256 + tid;
    if (i < BATCH * 34) stats[i] = 0.f;
  }
}

// ---- MLP ------------------------------------------------------------------
__global__ __launch_bounds__(256) void mlp_kernel(const float* __restrict__ stats,
                                                  const float* __restrict__ W1,
                                                  const float* __restrict__ b1,
                                                  const float* __restrict__ gamma,
                                                  const float* __restrict__ beta,
                                                  const float* __restrict__ W2m,
                                                  const float* __restrict__ b2,
                                                  float* __restrict__ out) {
  int bk = blockIdx.x;
  int b = bk >> 3, k = bk & 7;
  int e = threadIdx.x;

  __shared__ float st[34];
  if (e < 34) st[e] = stats[b * 34 + e];
  __syncthreads();

  const float N = (float)NPIX;
  float mu = st[0] / N;
  float varg = fmaxf(st[1] - N * mu * mu, 0.0f) / (N - 1.0f);
  float sd = sqrtf(varg) + 1e-6f;

  float s1r = st[2 + k], s2r = st[10 + k], mxr = st[18 + k], cntk = st[26 + k];
  float ms = cntk + 1e-6f;
  float s1n = (s1r - mu * cntk) / sd;
  float s2n = (s2r - 2.0f * mu * s1r + mu * mu * cntk) / (sd * sd);
  float mean_k = s1n / ms;
  float var_num = s2n - 2.0f * mean_k * s1n + mean_k * mean_k * cntk;
  float std_k = sqrtf(var_num / ms + 1e-6f);
  float max_k = (mxr - mu) / sd;

  float h = mean_k * W1[e] + std_k * W1[EDIM + e] + max_k * W1[2 * EDIM + e] + b1[e];

  float s = h, q = h * h;
#pragma unroll
  for (int off = 32; off > 0; off >>= 1) {
    s += __shfl_down(s, off);
    q += __shfl_down(q, off);
  }
  __shared__ float rs[4], rq[4];
  __shared__ float hmS, hvS;
  if ((e & 63) == 0) { rs[e >> 6] = s; rq[e >> 6] = q; }
  __syncthreads();
  if (e == 0) {
    float ts = rs[0] + rs[1] + rs[2] + rs[3];
    float tq = rq[0] + rq[1] + rq[2] + rq[3];
    float hm = ts / 256.0f;
    hmS = hm;
    hvS = fmaxf(tq / 256.0f - hm * hm, 0.0f);
  }
  __syncthreads();
  float hn = (h - hmS) / sqrtf(hvS + 1e-5f) * gamma[e] + beta[e];
  float hr = fmaxf(hn, 0.0f);

  __shared__ float hs[EDIM];
  hs[e] = hr;
  __syncthreads();

  float acc = b2[e];
#pragma unroll 8
  for (int j = 0; j < EDIM; j++) acc += hs[j] * W2m[j * EDIM + e];
  out[(size_t)bk * EDIM + e] = acc;
}

// ---- launch ---------------------------------------------------------------
extern "C" void kernel_launch(void* const* d_in, const int* in_sizes, int n_in,
                              void* d_out, int out_size, void* d_ws, size_t ws_size,
                              hipStream_t stream) {
  const float* x     = (const float*)d_in[0];
  const float* W1    = (const float*)d_in[1];
  const float* b1    = (const float*)d_in[2];
  const float* gamma = (const float*)d_in[3];
  const float* beta  = (const float*)d_in[4];
  const float* W2m   = (const float*)d_in[5];
  const float* b2    = (const float*)d_in[6];
  float* out = (float*)d_out;

  char* W = (char*)d_ws;
  f16* Gh  = (f16*)W;                                  // [14336][256] = 7,340,032 B
  f16* B2t = (f16*)(W + 7340032);                      // [64][128][448] = 7,340,032 B
  f16* B1  = (f16*)(W + 14680064);                     // [256][256]  = 131,072 B
  f16* W2h = (f16*)(W + 14680064 + 131072);            // [448][448]  = 401,408 B
  float* stats = (float*)(W + 14680064 + 131072 + 401408);  // 64*34 f32

  prep_kernel<<<dim3(16225), dim3(256), 0, stream>>>(x, Gh, B1, W2h, B2t, stats);
  gemmA_kernel<<<dim3(2, 224), dim3(256), 0, stream>>>(Gh, B1, B2t);
  gemmB_kernel<<<dim3(BATCH, 7), dim3(256), 0, stream>>>(W2h, B2t, stats);
  mlp_kernel<<<dim3(BATCH * 8), dim3(256), 0, stream>>>(stats, W1, b1, gamma, beta, W2m, b2, out);
}